// Round 1
// baseline (2379.517 us; speedup 1.0000x reference)
//
#include <hip/hip_runtime.h>
#include <math.h>

#define EPSF 1e-7f
constexpr int BB = 2, HH = 512, WWC = 512;

// ---------------------------------------------------------------------------
// Direct 3x3 conv, pad=1, fused bias + PReLU, register-tiled.
// Block = (64,4). Each thread computes YT output rows (same x) for OCT
// output channels. Weights for the block's OCT channels staged in LDS;
// each 9-weight LDS read is reused across YT rows (YT*9 FMAs per 3 ds_reads).
// ---------------------------------------------------------------------------
template <int S, int OCT, int YT>
__global__ __launch_bounds__(256) void conv3x3_prelu(
    const float* __restrict__ in, const float* __restrict__ wgt,
    const float* __restrict__ bias, const float* __restrict__ prelu_a,
    int aidx, float* __restrict__ out, int IC, int OC, int IH, int IW) {
    const int OH = IH / S, OW = IW / S;
    extern __shared__ float wsh[];  // OCT * IC * 9 floats
    const int oc0 = blockIdx.z * OCT;
    const int nw = OCT * IC * 9;
    const float* wsrc = wgt + (size_t)oc0 * IC * 9;
    for (int i = threadIdx.y * 64 + threadIdx.x; i < nw; i += 256)
        wsh[i] = wsrc[i];
    __syncthreads();

    const int ox = blockIdx.x * 64 + threadIdx.x;
    const int BROWS = 4 * YT;
    const int tiles_y = OH / BROWS;
    const int oy0 = (blockIdx.y % tiles_y) * BROWS + threadIdx.y * YT;
    const int b = blockIdx.y / tiles_y;

    float acc[OCT][YT];
#pragma unroll
    for (int j = 0; j < OCT; j++) {
        float bj = bias[oc0 + j];
#pragma unroll
        for (int yy = 0; yy < YT; yy++) acc[j][yy] = bj;
    }

    constexpr int R = YT * S + 2;  // input rows needed
    const float* inb = in + (size_t)b * IC * IH * IW;
    const int iy0 = oy0 * S - 1, ix0 = ox * S - 1;

    for (int ic = 0; ic < IC; ic++) {
        const float* ip = inb + (size_t)ic * IH * IW;
        float v[R][3];
#pragma unroll
        for (int r = 0; r < R; r++) {
            const int iy = iy0 + r;
            const bool yok = (unsigned)iy < (unsigned)IH;
            const float* rp = ip + iy * IW;
#pragma unroll
            for (int c = 0; c < 3; c++) {
                const int ix = ix0 + c;
                v[r][c] = (yok && (unsigned)ix < (unsigned)IW) ? rp[ix] : 0.f;
            }
        }
#pragma unroll
        for (int j = 0; j < OCT; j++) {
            const float* wj = wsh + (j * IC + ic) * 9;
            float w[9];
#pragma unroll
            for (int k = 0; k < 9; k++) w[k] = wj[k];
#pragma unroll
            for (int yy = 0; yy < YT; yy++) {
                float a = acc[j][yy];
#pragma unroll
                for (int ky = 0; ky < 3; ky++)
#pragma unroll
                    for (int kx = 0; kx < 3; kx++)
                        a = fmaf(v[yy * S + ky][kx], w[ky * 3 + kx], a);
                acc[j][yy] = a;
            }
        }
    }
    const float al = prelu_a[aidx];
    float* ob = out + (((size_t)b * OC + oc0) * OH + oy0) * OW + ox;
#pragma unroll
    for (int j = 0; j < OCT; j++)
#pragma unroll
        for (int yy = 0; yy < YT; yy++) {
            float y = acc[j][yy];
            y = y >= 0.f ? y : al * y;
            ob[(size_t)j * OH * OW + (size_t)yy * OW] = y;
        }
}

// ---------------------------------------------------------------------------
// z = param_scale * mean_c |(2*i0-1) - backwarp(2*i1-1, flow)| for BOTH
// directions in one launch (blockIdx.y = direction).
// ---------------------------------------------------------------------------
__global__ void compute_z2_kernel(const float* __restrict__ in0,
                                  const float* __restrict__ in1,
                                  const float* __restrict__ f01,
                                  const float* __restrict__ f10,
                                  const float* __restrict__ pscale,
                                  float* __restrict__ z0,
                                  float* __restrict__ z1) {
    int idx = blockIdx.x * blockDim.x + threadIdx.x;
    const int n = BB * HH * WWC;
    if (idx >= n) return;
    const int dir = blockIdx.y;
    const float* i0 = dir ? in1 : in0;
    const float* i1 = dir ? in0 : in1;
    const float* flow = dir ? f10 : f01;
    float* z = dir ? z1 : z0;
    int x = idx % WWC, y = (idx / WWC) % HH, b = idx / (WWC * HH);
    const float* fb = flow + (size_t)b * 2 * HH * WWC;
    float fx = fb[y * WWC + x];
    float fy = fb[HH * WWC + y * WWC + x];
    float px = fminf(fmaxf(x + fx, 0.f), WWC - 1.f);
    float py = fminf(fmaxf(y + fy, 0.f), HH - 1.f);
    float x0f = floorf(px), y0f = floorf(py);
    int x0 = (int)x0f, y0 = (int)y0f;
    int x1 = min(x0 + 1, WWC - 1), y1 = min(y0 + 1, HH - 1);
    float wx = px - x0f, wy = py - y0f;
    float w00 = (1.f - wx) * (1.f - wy), w10 = wx * (1.f - wy);
    float w01 = (1.f - wx) * wy, w11 = wx * wy;
    const float* ib0 = i0 + (size_t)b * 3 * HH * WWC;
    const float* ib1 = i1 + (size_t)b * 3 * HH * WWC;
    float err = 0.f;
#pragma unroll
    for (int c = 0; c < 3; c++) {
        const float* sp = ib1 + (size_t)c * HH * WWC;
        float wv = sp[y0 * WWC + x0] * w00 + sp[y0 * WWC + x1] * w10 +
                   sp[y1 * WWC + x0] * w01 + sp[y1 * WWC + x1] * w11;
        float p0 = 2.f * ib0[(size_t)c * HH * WWC + y * WWC + x] - 1.f;
        err += fabsf(p0 - (2.f * wv - 1.f));
    }
    z[idx] = pscale[0] * (err * (1.f / 3.f));
}

__device__ inline void atomic_add_f32(float* p, float v) {
    __hip_atomic_fetch_add(p, v, __ATOMIC_RELAXED, __HIP_MEMORY_SCOPE_AGENT);
}

// ---------------------------------------------------------------------------
// Forward splat of (-f * e^z, e^z) with flow f = tt*flow_in; z resampled
// bilinearly (half-pixel coords) for s>0.
// acc layout is CHANNEL-INTERLEAVED: (B, hh, ww, 3) = (vx, vy, ez) per pixel,
// so the 3 atomics per corner land in one (or at most two) 32B L2 sectors
// instead of 3 distant cache lines -> ~2.4x less atomic write-through traffic.
// ---------------------------------------------------------------------------
__global__ void splat_kernel(const float* __restrict__ flow,
                             const float* __restrict__ z,
                             const float* __restrict__ tptr, int dir,
                             float* __restrict__ acc, int s, int hh, int ww) {
    int idx = blockIdx.x * blockDim.x + threadIdx.x;
    const int n = BB * hh * ww;
    if (idx >= n) return;
    int x = idx % ww, y = (idx / ww) % hh, b = idx / (ww * hh);
    float tt = tptr[b];
    if (dir) tt = 1.f - tt;
    const float* fb = flow + (size_t)b * 2 * hh * ww;
    float fx = tt * fb[y * ww + x];
    float fy = tt * fb[hh * ww + y * ww + x];
    float zz;
    if (s == 0) {
        zz = z[((size_t)b * HH + y) * WWC + x];
    } else {
        float sc = (float)(1 << s);
        float px = fminf(fmaxf((x + 0.5f) * sc - 0.5f, 0.f), WWC - 1.f);
        float py = fminf(fmaxf((y + 0.5f) * sc - 0.5f, 0.f), HH - 1.f);
        float x0f = floorf(px), y0f = floorf(py);
        int x0 = (int)x0f, y0 = (int)y0f;
        int x1 = min(x0 + 1, WWC - 1), y1 = min(y0 + 1, HH - 1);
        float wx = px - x0f, wy = py - y0f;
        const float* zp = z + (size_t)b * HH * WWC;
        zz = zp[y0 * WWC + x0] * (1.f - wx) * (1.f - wy) +
             zp[y0 * WWC + x1] * wx * (1.f - wy) +
             zp[y1 * WWC + x0] * (1.f - wx) * wy + zp[y1 * WWC + x1] * wx * wy;
    }
    float ez = expf(zz);
    float vx = -fx * ez, vy = -fy * ez;
    float tx = x + fx, ty = y + fy;
    float x0f = floorf(tx), y0f = floorf(ty);
    int x0 = (int)x0f, y0 = (int)y0f;
    int x1 = x0 + 1, y1 = y0 + 1;
    float wx1 = tx - x0f, wy1 = ty - y0f;
    float wx0 = 1.f - wx1, wy0 = 1.f - wy1;
    float* ab = acc + (size_t)b * 3 * hh * ww;
    int cxs[4] = {x0, x1, x0, x1};
    int cys[4] = {y0, y0, y1, y1};
    float cws[4] = {wx0 * wy0, wx1 * wy0, wx0 * wy1, wx1 * wy1};
#pragma unroll
    for (int k = 0; k < 4; k++) {
        int cx = cxs[k], cy = cys[k];
        float w = cws[k];
        if (cx >= 0 && cx < ww && cy >= 0 && cy < hh && w != 0.f) {
            float* p = ab + (size_t)3 * (cy * ww + cx);
            atomic_add_f32(p, vx * w);
            atomic_add_f32(p + 1, vy * w);
            atomic_add_f32(p + 2, ez * w);
        }
    }
}

// ---------------------------------------------------------------------------
// flow_t0 = acc[0:2]/(acc[2]+eps); out[:,coff:coff+C] = backwarp(src, flow_t0)
// acc is channel-interleaved (B, hh, ww, 3).
// ---------------------------------------------------------------------------
__global__ void backwarp_out_kernel(const float* __restrict__ acc,
                                    const float* __restrict__ src,
                                    float* __restrict__ out, int C, int hh,
                                    int ww, int OCL, int coff) {
    int idx = blockIdx.x * blockDim.x + threadIdx.x;
    const int n = BB * hh * ww;
    if (idx >= n) return;
    int x = idx % ww, y = (idx / ww) % hh, b = idx / (ww * hh);
    const int plane = hh * ww;
    const float* ab = acc + (size_t)b * 3 * plane;
    int o = y * ww + x;
    const float* ap = ab + (size_t)3 * o;
    float den = ap[2] + EPSF;
    float fx = ap[0] / den;
    float fy = ap[1] / den;
    float px = fminf(fmaxf(x + fx, 0.f), ww - 1.f);
    float py = fminf(fmaxf(y + fy, 0.f), hh - 1.f);
    float x0f = floorf(px), y0f = floorf(py);
    int x0 = (int)x0f, y0 = (int)y0f;
    int x1 = min(x0 + 1, ww - 1), y1 = min(y0 + 1, hh - 1);
    float wx = px - x0f, wy = py - y0f;
    float w00 = (1.f - wx) * (1.f - wy), w10 = wx * (1.f - wy);
    float w01 = (1.f - wx) * wy, w11 = wx * wy;
    int i00 = y0 * ww + x0, i10 = y0 * ww + x1, i01 = y1 * ww + x0,
        i11 = y1 * ww + x1;
    const float* sb = src + (size_t)b * C * plane;
    float* ob = out + (((size_t)b * OCL + coff) * (size_t)plane) + o;
    for (int c = 0; c < C; c++) {
        const float* sp = sb + (size_t)c * plane;
        float v = sp[i00] * w00 + sp[i10] * w10 + sp[i01] * w01 + sp[i11] * w11;
        ob[(size_t)c * plane] = v;
    }
}

// ---------------------------------------------------------------------------
extern "C" void kernel_launch(void* const* d_in, const int* in_sizes, int n_in,
                              void* d_out, int out_size, void* d_ws,
                              size_t ws_size, hipStream_t stream) {
    const float* input0 = (const float*)d_in[0];
    const float* input1 = (const float*)d_in[1];
    const float* tgt = (const float*)d_in[2];
    const float* flows[2][3] = {
        {(const float*)d_in[3], (const float*)d_in[4], (const float*)d_in[5]},
        {(const float*)d_in[6], (const float*)d_in[7], (const float*)d_in[8]}};
    const float* w[6];
    const float* bs[6];
    for (int i = 0; i < 6; i++) {
        w[i] = (const float*)d_in[9 + 2 * i];
        bs[i] = (const float*)d_in[10 + 2 * i];
    }
    const float* prelu_a = (const float*)d_in[21];
    const float* pscale = (const float*)d_in[22];
    float* out = (float*)d_out;
    float* wsp = (float*)d_ws;

    // Workspace layout (floats): 59,244,544 total (~237 MB)
    float* fea1[2] = {wsp, wsp + 16777216};              // (2,32,512,512) each
    float* fea2[2] = {wsp + 33554432, wsp + 41943040};   // (2,64,256,256) each
    float* fea3[2] = {wsp + 50331648, wsp + 53477376};   // (2,96,128,128) each
    float* zb[2] = {wsp + 56623104, wsp + 57147392};     // (2,512,512) each
    float* acc = wsp + 57671680;                          // (2,512,512,3) intl
    float* tmp = out;  // conv ping-pong scratch; overwritten by outputs later

    // conv<STRIDE, OCT(out-ch/thread), YT(rows/thread)>
    auto conv = [&](int stride, int oct, int yt, const float* in, int li,
                    float* o, int IC, int OC, int IH, int IW) {
        int OH = IH / stride, OW = IW / stride;
        int brows = 4 * yt;
        dim3 blk(64, 4);
        dim3 grd(OW / 64, (OH / brows) * BB, OC / oct);
        size_t sm = (size_t)oct * IC * 9 * sizeof(float);
        if (stride == 1 && oct == 16 && yt == 4)
            conv3x3_prelu<1, 16, 4><<<grd, blk, sm, stream>>>(
                in, w[li], bs[li], prelu_a, li, o, IC, OC, IH, IW);
        else if (stride == 2 && oct == 16 && yt == 4)
            conv3x3_prelu<2, 16, 4><<<grd, blk, sm, stream>>>(
                in, w[li], bs[li], prelu_a, li, o, IC, OC, IH, IW);
        else if (stride == 2 && oct == 8 && yt == 2)
            conv3x3_prelu<2, 8, 2><<<grd, blk, sm, stream>>>(
                in, w[li], bs[li], prelu_a, li, o, IC, OC, IH, IW);
        else
            conv3x3_prelu<1, 8, 2><<<grd, blk, sm, stream>>>(
                in, w[li], bs[li], prelu_a, li, o, IC, OC, IH, IW);
    };

    const float* inp[2] = {input0, input1};
    for (int i = 0; i < 2; i++) {
        conv(1, 16, 4, inp[i], 0, tmp, 3, 32, 512, 512);
        conv(1, 16, 4, tmp, 1, fea1[i], 32, 32, 512, 512);
        conv(2, 16, 4, fea1[i], 2, tmp, 32, 64, 512, 512);
        conv(1, 16, 4, tmp, 3, fea2[i], 64, 64, 256, 256);
        conv(2, 8, 2, fea2[i], 4, tmp, 64, 96, 256, 256);
        conv(1, 8, 2, tmp, 5, fea3[i], 96, 96, 128, 128);
    }

    {
        int n = BB * HH * WWC;
        dim3 grd((n + 255) / 256, 2);
        compute_z2_kernel<<<grd, 256, 0, stream>>>(
            input0, input1, flows[0][0], flows[1][0], pscale, zb[0], zb[1]);
    }

    const size_t l1off = (size_t)BB * 70 * 512 * 512;            // 36,700,160
    const size_t l2off = l1off + (size_t)BB * 128 * 256 * 256;   // 53,477,376

    for (int d = 0; d < 2; d++) {
        for (int s = 0; s < 3; s++) {
            int hh = HH >> s, ww = WWC >> s;
            int n = BB * hh * ww;
            hipMemsetAsync(acc, 0, (size_t)BB * 3 * hh * ww * sizeof(float),
                           stream);
            splat_kernel<<<(n + 255) / 256, 256, 0, stream>>>(
                flows[d][s], zb[d], tgt, d, acc, s, hh, ww);
            if (s == 0) {
                backwarp_out_kernel<<<(n + 255) / 256, 256, 0, stream>>>(
                    acc, inp[d], out, 3, 512, 512, 70, d ? 35 : 0);
                backwarp_out_kernel<<<(n + 255) / 256, 256, 0, stream>>>(
                    acc, fea1[d], out, 32, 512, 512, 70, d ? 38 : 3);
            } else if (s == 1) {
                backwarp_out_kernel<<<(n + 255) / 256, 256, 0, stream>>>(
                    acc, fea2[d], out + l1off, 64, 256, 256, 128, d ? 64 : 0);
            } else {
                backwarp_out_kernel<<<(n + 255) / 256, 256, 0, stream>>>(
                    acc, fea3[d], out + l2off, 96, 128, 128, 192, d ? 96 : 0);
            }
        }
    }
}

// Round 2
// 2015.168 us; speedup vs baseline: 1.1808x; 1.1808x over previous
//
#include <hip/hip_runtime.h>
#include <math.h>

#define EPSF 1e-7f
constexpr int BB = 2, HH = 512, WWC = 512;

// ---------------------------------------------------------------------------
// Direct 3x3 conv, pad=1, fused bias + PReLU, register-tiled.
// Block = (64,4). Each thread computes YT output rows (same x) for OCT
// output channels. Weights for the block's OCT channels staged in LDS;
// each 9-weight LDS read is reused across YT rows (YT*9 FMAs per 3 ds_reads).
// ---------------------------------------------------------------------------
template <int S, int OCT, int YT>
__global__ __launch_bounds__(256) void conv3x3_prelu(
    const float* __restrict__ in, const float* __restrict__ wgt,
    const float* __restrict__ bias, const float* __restrict__ prelu_a,
    int aidx, float* __restrict__ out, int IC, int OC, int IH, int IW) {
    const int OH = IH / S, OW = IW / S;
    extern __shared__ float wsh[];  // OCT * IC * 9 floats
    const int oc0 = blockIdx.z * OCT;
    const int nw = OCT * IC * 9;
    const float* wsrc = wgt + (size_t)oc0 * IC * 9;
    for (int i = threadIdx.y * 64 + threadIdx.x; i < nw; i += 256)
        wsh[i] = wsrc[i];
    __syncthreads();

    const int ox = blockIdx.x * 64 + threadIdx.x;
    const int BROWS = 4 * YT;
    const int tiles_y = OH / BROWS;
    const int oy0 = (blockIdx.y % tiles_y) * BROWS + threadIdx.y * YT;
    const int b = blockIdx.y / tiles_y;

    float acc[OCT][YT];
#pragma unroll
    for (int j = 0; j < OCT; j++) {
        float bj = bias[oc0 + j];
#pragma unroll
        for (int yy = 0; yy < YT; yy++) acc[j][yy] = bj;
    }

    constexpr int R = YT * S + 2;  // input rows needed
    const float* inb = in + (size_t)b * IC * IH * IW;
    const int iy0 = oy0 * S - 1, ix0 = ox * S - 1;

    for (int ic = 0; ic < IC; ic++) {
        const float* ip = inb + (size_t)ic * IH * IW;
        float v[R][3];
#pragma unroll
        for (int r = 0; r < R; r++) {
            const int iy = iy0 + r;
            const bool yok = (unsigned)iy < (unsigned)IH;
            const float* rp = ip + iy * IW;
#pragma unroll
            for (int c = 0; c < 3; c++) {
                const int ix = ix0 + c;
                v[r][c] = (yok && (unsigned)ix < (unsigned)IW) ? rp[ix] : 0.f;
            }
        }
#pragma unroll
        for (int j = 0; j < OCT; j++) {
            const float* wj = wsh + (j * IC + ic) * 9;
            float w[9];
#pragma unroll
            for (int k = 0; k < 9; k++) w[k] = wj[k];
#pragma unroll
            for (int yy = 0; yy < YT; yy++) {
                float a = acc[j][yy];
#pragma unroll
                for (int ky = 0; ky < 3; ky++)
#pragma unroll
                    for (int kx = 0; kx < 3; kx++)
                        a = fmaf(v[yy * S + ky][kx], w[ky * 3 + kx], a);
                acc[j][yy] = a;
            }
        }
    }
    const float al = prelu_a[aidx];
    float* ob = out + (((size_t)b * OC + oc0) * OH + oy0) * OW + ox;
#pragma unroll
    for (int j = 0; j < OCT; j++)
#pragma unroll
        for (int yy = 0; yy < YT; yy++) {
            float y = acc[j][yy];
            y = y >= 0.f ? y : al * y;
            ob[(size_t)j * OH * OW + (size_t)yy * OW] = y;
        }
}

// ---------------------------------------------------------------------------
// z = param_scale * mean_c |(2*i0-1) - backwarp(2*i1-1, flow)| for BOTH
// directions in one launch (blockIdx.y = direction).
// ---------------------------------------------------------------------------
__global__ void compute_z2_kernel(const float* __restrict__ in0,
                                  const float* __restrict__ in1,
                                  const float* __restrict__ f01,
                                  const float* __restrict__ f10,
                                  const float* __restrict__ pscale,
                                  float* __restrict__ z0,
                                  float* __restrict__ z1) {
    int idx = blockIdx.x * blockDim.x + threadIdx.x;
    const int n = BB * HH * WWC;
    if (idx >= n) return;
    const int dir = blockIdx.y;
    const float* i0 = dir ? in1 : in0;
    const float* i1 = dir ? in0 : in1;
    const float* flow = dir ? f10 : f01;
    float* z = dir ? z1 : z0;
    int x = idx % WWC, y = (idx / WWC) % HH, b = idx / (WWC * HH);
    const float* fb = flow + (size_t)b * 2 * HH * WWC;
    float fx = fb[y * WWC + x];
    float fy = fb[HH * WWC + y * WWC + x];
    float px = fminf(fmaxf(x + fx, 0.f), WWC - 1.f);
    float py = fminf(fmaxf(y + fy, 0.f), HH - 1.f);
    float x0f = floorf(px), y0f = floorf(py);
    int x0 = (int)x0f, y0 = (int)y0f;
    int x1 = min(x0 + 1, WWC - 1), y1 = min(y0 + 1, HH - 1);
    float wx = px - x0f, wy = py - y0f;
    float w00 = (1.f - wx) * (1.f - wy), w10 = wx * (1.f - wy);
    float w01 = (1.f - wx) * wy, w11 = wx * wy;
    const float* ib0 = i0 + (size_t)b * 3 * HH * WWC;
    const float* ib1 = i1 + (size_t)b * 3 * HH * WWC;
    float err = 0.f;
#pragma unroll
    for (int c = 0; c < 3; c++) {
        const float* sp = ib1 + (size_t)c * HH * WWC;
        float wv = sp[y0 * WWC + x0] * w00 + sp[y0 * WWC + x1] * w10 +
                   sp[y1 * WWC + x0] * w01 + sp[y1 * WWC + x1] * w11;
        float p0 = 2.f * ib0[(size_t)c * HH * WWC + y * WWC + x] - 1.f;
        err += fabsf(p0 - (2.f * wv - 1.f));
    }
    z[idx] = pscale[0] * (err * (1.f / 3.f));
}

__device__ inline void atomic_add_f32(float* p, float v) {
    __hip_atomic_fetch_add(p, v, __ATOMIC_RELAXED, __HIP_MEMORY_SCOPE_AGENT);
}

// ---------------------------------------------------------------------------
// Shared helper: z value (resampled bilinearly for s>0) for source (sx,sy).
// z is always full-res (B,512,512).
// ---------------------------------------------------------------------------
__device__ inline float z_sample(const float* __restrict__ zb, int b, int sx,
                                 int sy, int s) {
    const float* zp = zb + (size_t)b * HH * WWC;
    if (s == 0) return zp[sy * WWC + sx];
    float sc = (float)(1 << s);
    float px = fminf(fmaxf((sx + 0.5f) * sc - 0.5f, 0.f), WWC - 1.f);
    float py = fminf(fmaxf((sy + 0.5f) * sc - 0.5f, 0.f), HH - 1.f);
    float x0f = floorf(px), y0f = floorf(py);
    int x0 = (int)x0f, y0 = (int)y0f;
    int x1 = min(x0 + 1, WWC - 1), y1 = min(y0 + 1, HH - 1);
    float wx = px - x0f, wy = py - y0f;
    return zp[y0 * WWC + x0] * (1.f - wx) * (1.f - wy) +
           zp[y0 * WWC + x1] * wx * (1.f - wy) +
           zp[y1 * WWC + x0] * (1.f - wx) * wy + zp[y1 * WWC + x1] * wx * wy;
}

// ---------------------------------------------------------------------------
// FAR pass: sources with |fx|>15 or |fy|>15 (rare) use the original global-
// atomic scatter. Classification is the identical float expression as in the
// gather pass, so every (source,corner) is handled exactly once.
// acc layout channel-interleaved: (B, hh, ww, 3) = (vx, vy, ez).
// ---------------------------------------------------------------------------
__global__ void splat_far_kernel(const float* __restrict__ flow,
                                 const float* __restrict__ z,
                                 const float* __restrict__ tptr, int dir,
                                 float* __restrict__ acc, int s, int hh,
                                 int ww) {
    int idx = blockIdx.x * blockDim.x + threadIdx.x;
    const int n = BB * hh * ww;
    if (idx >= n) return;
    int x = idx % ww, y = (idx / ww) % hh, b = idx / (ww * hh);
    float tt = tptr[b];
    if (dir) tt = 1.f - tt;
    const float* fb = flow + (size_t)b * 2 * hh * ww;
    float fx = tt * fb[y * ww + x];
    float fy = tt * fb[hh * ww + y * ww + x];
    if (fmaxf(fabsf(fx), fabsf(fy)) <= 15.f) return;  // near -> gather pass
    float zz = z_sample(z, b, x, y, s);
    float ez = expf(zz);
    float vx = -fx * ez, vy = -fy * ez;
    float tx = x + fx, ty = y + fy;
    float x0f = floorf(tx), y0f = floorf(ty);
    int x0 = (int)x0f, y0 = (int)y0f;
    int x1 = x0 + 1, y1 = y0 + 1;
    float wx1 = tx - x0f, wy1 = ty - y0f;
    float wx0 = 1.f - wx1, wy0 = 1.f - wy1;
    float* ab = acc + (size_t)b * 3 * hh * ww;
    int cxs[4] = {x0, x1, x0, x1};
    int cys[4] = {y0, y0, y1, y1};
    float cws[4] = {wx0 * wy0, wx1 * wy0, wx0 * wy1, wx1 * wy1};
#pragma unroll
    for (int k = 0; k < 4; k++) {
        int cx = cxs[k], cy = cys[k];
        float w = cws[k];
        if (cx >= 0 && cx < ww && cy >= 0 && cy < hh && w != 0.f) {
            float* p = ab + (size_t)3 * (cy * ww + cx);
            atomic_add_f32(p, vx * w);
            atomic_add_f32(p + 1, vy * w);
            atomic_add_f32(p + 2, ez * w);
        }
    }
}

// ---------------------------------------------------------------------------
// NEAR pass (gather): each block owns a disjoint TH x TW output tile,
// gathers all sources within a +/-16 halo, accumulates 4-corner splat
// contributions into LDS (ds_add_f32), then does a plain coalesced RMW
// flush (acc already holds the far-pass contributions). No global atomics.
// ---------------------------------------------------------------------------
template <int TH, int TW>
__global__ __launch_bounds__(256) void splat_gather_kernel(
    const float* __restrict__ flow, const float* __restrict__ z,
    const float* __restrict__ tptr, int dir, float* __restrict__ acc, int s,
    int hh, int ww) {
    constexpr int HALO = 16;
    constexpr int RH = TH + 2 * HALO, RW = TW + 2 * HALO;
    __shared__ float lacc[TH * TW * 3];
    const int x0 = blockIdx.x * TW, y0 = blockIdx.y * TH;
    const int b = blockIdx.z;
    const int tid = threadIdx.x;
    for (int i = tid; i < TH * TW * 3; i += 256) lacc[i] = 0.f;
    __syncthreads();
    float tt = tptr[b];
    if (dir) tt = 1.f - tt;
    const float* fb = flow + (size_t)b * 2 * hh * ww;
    for (int i = tid; i < RH * RW; i += 256) {
        int sy = y0 - HALO + i / RW;
        int sx = x0 - HALO + i % RW;
        if ((unsigned)sy >= (unsigned)hh || (unsigned)sx >= (unsigned)ww)
            continue;
        float fx = tt * fb[sy * ww + sx];
        float fy = tt * fb[(size_t)hh * ww + sy * ww + sx];
        if (fmaxf(fabsf(fx), fabsf(fy)) > 15.f) continue;  // far pass handles
        float zz = z_sample(z, b, sx, sy, s);
        float ez = expf(zz);
        float vx = -fx * ez, vy = -fy * ez;
        float tx = sx + fx, ty = sy + fy;
        float xf = floorf(tx), yf = floorf(ty);
        int cx0 = (int)xf - x0, cy0 = (int)yf - y0;  // tile-local corner 0
        float wx1 = tx - xf, wy1 = ty - yf;
        float wx0 = 1.f - wx1, wy0 = 1.f - wy1;
#pragma unroll
        for (int k = 0; k < 4; k++) {
            int cx = cx0 + (k & 1), cy = cy0 + (k >> 1);
            float wgt = ((k & 1) ? wx1 : wx0) * ((k >> 1) ? wy1 : wy0);
            if ((unsigned)cx < (unsigned)TW && (unsigned)cy < (unsigned)TH &&
                wgt != 0.f) {
                float* p = lacc + (cy * TW + cx) * 3;
                atomicAdd(p, vx * wgt);
                atomicAdd(p + 1, vy * wgt);
                atomicAdd(p + 2, ez * wgt);
            }
        }
    }
    __syncthreads();
    // Disjoint-tile flush: plain read-modify-write, fully coalesced.
    float* ab = acc + (((size_t)b * hh + y0) * ww + x0) * 3;
    for (int i = tid; i < TH * TW * 3; i += 256) {
        int row = i / (TW * 3), rem = i % (TW * 3);
        float* gp = ab + (size_t)row * ww * 3 + rem;
        *gp = *gp + lacc[i];
    }
}

// ---------------------------------------------------------------------------
// flow_t0 = acc[0:2]/(acc[2]+eps); out[:,coff:coff+C] = backwarp(src, flow_t0)
// acc is channel-interleaved (B, hh, ww, 3).
// ---------------------------------------------------------------------------
__global__ void backwarp_out_kernel(const float* __restrict__ acc,
                                    const float* __restrict__ src,
                                    float* __restrict__ out, int C, int hh,
                                    int ww, int OCL, int coff) {
    int idx = blockIdx.x * blockDim.x + threadIdx.x;
    const int n = BB * hh * ww;
    if (idx >= n) return;
    int x = idx % ww, y = (idx / ww) % hh, b = idx / (ww * hh);
    const int plane = hh * ww;
    const float* ab = acc + (size_t)b * 3 * plane;
    int o = y * ww + x;
    const float* ap = ab + (size_t)3 * o;
    float den = ap[2] + EPSF;
    float fx = ap[0] / den;
    float fy = ap[1] / den;
    float px = fminf(fmaxf(x + fx, 0.f), ww - 1.f);
    float py = fminf(fmaxf(y + fy, 0.f), hh - 1.f);
    float x0f = floorf(px), y0f = floorf(py);
    int x0 = (int)x0f, y0 = (int)y0f;
    int x1 = min(x0 + 1, ww - 1), y1 = min(y0 + 1, hh - 1);
    float wx = px - x0f, wy = py - y0f;
    float w00 = (1.f - wx) * (1.f - wy), w10 = wx * (1.f - wy);
    float w01 = (1.f - wx) * wy, w11 = wx * wy;
    int i00 = y0 * ww + x0, i10 = y0 * ww + x1, i01 = y1 * ww + x0,
        i11 = y1 * ww + x1;
    const float* sb = src + (size_t)b * C * plane;
    float* ob = out + (((size_t)b * OCL + coff) * (size_t)plane) + o;
    for (int c = 0; c < C; c++) {
        const float* sp = sb + (size_t)c * plane;
        float v = sp[i00] * w00 + sp[i10] * w10 + sp[i01] * w01 + sp[i11] * w11;
        ob[(size_t)c * plane] = v;
    }
}

// ---------------------------------------------------------------------------
extern "C" void kernel_launch(void* const* d_in, const int* in_sizes, int n_in,
                              void* d_out, int out_size, void* d_ws,
                              size_t ws_size, hipStream_t stream) {
    const float* input0 = (const float*)d_in[0];
    const float* input1 = (const float*)d_in[1];
    const float* tgt = (const float*)d_in[2];
    const float* flows[2][3] = {
        {(const float*)d_in[3], (const float*)d_in[4], (const float*)d_in[5]},
        {(const float*)d_in[6], (const float*)d_in[7], (const float*)d_in[8]}};
    const float* w[6];
    const float* bs[6];
    for (int i = 0; i < 6; i++) {
        w[i] = (const float*)d_in[9 + 2 * i];
        bs[i] = (const float*)d_in[10 + 2 * i];
    }
    const float* prelu_a = (const float*)d_in[21];
    const float* pscale = (const float*)d_in[22];
    float* out = (float*)d_out;
    float* wsp = (float*)d_ws;

    // Workspace layout (floats): 59,244,544 total (~237 MB)
    float* fea1[2] = {wsp, wsp + 16777216};              // (2,32,512,512) each
    float* fea2[2] = {wsp + 33554432, wsp + 41943040};   // (2,64,256,256) each
    float* fea3[2] = {wsp + 50331648, wsp + 53477376};   // (2,96,128,128) each
    float* zb[2] = {wsp + 56623104, wsp + 57147392};     // (2,512,512) each
    float* acc = wsp + 57671680;                          // (2,512,512,3) intl
    float* tmp = out;  // conv ping-pong scratch; overwritten by outputs later

    // conv<STRIDE, OCT(out-ch/thread), YT(rows/thread)>
    auto conv = [&](int stride, int oct, int yt, const float* in, int li,
                    float* o, int IC, int OC, int IH, int IW) {
        int OH = IH / stride, OW = IW / stride;
        int brows = 4 * yt;
        dim3 blk(64, 4);
        dim3 grd(OW / 64, (OH / brows) * BB, OC / oct);
        size_t sm = (size_t)oct * IC * 9 * sizeof(float);
        if (stride == 1 && oct == 16 && yt == 4)
            conv3x3_prelu<1, 16, 4><<<grd, blk, sm, stream>>>(
                in, w[li], bs[li], prelu_a, li, o, IC, OC, IH, IW);
        else if (stride == 2 && oct == 16 && yt == 4)
            conv3x3_prelu<2, 16, 4><<<grd, blk, sm, stream>>>(
                in, w[li], bs[li], prelu_a, li, o, IC, OC, IH, IW);
        else if (stride == 2 && oct == 8 && yt == 2)
            conv3x3_prelu<2, 8, 2><<<grd, blk, sm, stream>>>(
                in, w[li], bs[li], prelu_a, li, o, IC, OC, IH, IW);
        else
            conv3x3_prelu<1, 8, 2><<<grd, blk, sm, stream>>>(
                in, w[li], bs[li], prelu_a, li, o, IC, OC, IH, IW);
    };

    const float* inp[2] = {input0, input1};
    for (int i = 0; i < 2; i++) {
        conv(1, 16, 4, inp[i], 0, tmp, 3, 32, 512, 512);
        conv(1, 16, 4, tmp, 1, fea1[i], 32, 32, 512, 512);
        conv(2, 16, 4, fea1[i], 2, tmp, 32, 64, 512, 512);
        conv(1, 16, 4, tmp, 3, fea2[i], 64, 64, 256, 256);
        conv(2, 8, 2, fea2[i], 4, tmp, 64, 96, 256, 256);
        conv(1, 8, 2, tmp, 5, fea3[i], 96, 96, 128, 128);
    }

    {
        int n = BB * HH * WWC;
        dim3 grd((n + 255) / 256, 2);
        compute_z2_kernel<<<grd, 256, 0, stream>>>(
            input0, input1, flows[0][0], flows[1][0], pscale, zb[0], zb[1]);
    }

    const size_t l1off = (size_t)BB * 70 * 512 * 512;            // 36,700,160
    const size_t l2off = l1off + (size_t)BB * 128 * 256 * 256;   // 53,477,376

    for (int d = 0; d < 2; d++) {
        for (int s = 0; s < 3; s++) {
            int hh = HH >> s, ww = WWC >> s;
            int n = BB * hh * ww;
            hipMemsetAsync(acc, 0, (size_t)BB * 3 * hh * ww * sizeof(float),
                           stream);
            splat_far_kernel<<<(n + 255) / 256, 256, 0, stream>>>(
                flows[d][s], zb[d], tgt, d, acc, s, hh, ww);
            if (s < 2) {
                dim3 grd(ww / 64, hh / 32, BB);
                splat_gather_kernel<32, 64><<<grd, 256, 0, stream>>>(
                    flows[d][s], zb[d], tgt, d, acc, s, hh, ww);
            } else {
                dim3 grd(ww / 32, hh / 16, BB);
                splat_gather_kernel<16, 32><<<grd, 256, 0, stream>>>(
                    flows[d][s], zb[d], tgt, d, acc, s, hh, ww);
            }
            if (s == 0) {
                backwarp_out_kernel<<<(n + 255) / 256, 256, 0, stream>>>(
                    acc, inp[d], out, 3, 512, 512, 70, d ? 35 : 0);
                backwarp_out_kernel<<<(n + 255) / 256, 256, 0, stream>>>(
                    acc, fea1[d], out, 32, 512, 512, 70, d ? 38 : 3);
            } else if (s == 1) {
                backwarp_out_kernel<<<(n + 255) / 256, 256, 0, stream>>>(
                    acc, fea2[d], out + l1off, 64, 256, 256, 128, d ? 64 : 0);
            } else {
                backwarp_out_kernel<<<(n + 255) / 256, 256, 0, stream>>>(
                    acc, fea3[d], out + l2off, 96, 128, 128, 192, d ? 96 : 0);
            }
        }
    }
}

// Round 3
// 1444.212 us; speedup vs baseline: 1.6476x; 1.3953x over previous
//
#include <hip/hip_runtime.h>
#include <math.h>

#define EPSF 1e-7f
constexpr int BB = 2, HH = 512, WWC = 512;

typedef __attribute__((ext_vector_type(4))) float f32x4;
typedef __attribute__((ext_vector_type(8))) _Float16 half8;

// ---------------------------------------------------------------------------
// conv1 only (IC=3): direct fp32 conv, pad=1, fused bias+PReLU, output
// written as PADDED NHWC f16 (halo ring pre-zeroed by memset).
// Block (64,4); OCT out-channels x YT rows per thread.
// ---------------------------------------------------------------------------
template <int OCT, int YT>
__global__ __launch_bounds__(256) void conv3x3_nhwc(
    const float* __restrict__ in, const float* __restrict__ wgt,
    const float* __restrict__ bias, const float* __restrict__ prelu_a,
    int aidx, _Float16* __restrict__ out, int IC, int OC, int IH, int IW,
    int OWp) {
    const int OH = IH, OW = IW;
    extern __shared__ float wsh[];
    const int oc0 = blockIdx.z * OCT;
    const int nw = OCT * IC * 9;
    const float* wsrc = wgt + (size_t)oc0 * IC * 9;
    for (int i = threadIdx.y * 64 + threadIdx.x; i < nw; i += 256)
        wsh[i] = wsrc[i];
    __syncthreads();

    const int ox = blockIdx.x * 64 + threadIdx.x;
    const int BROWS = 4 * YT;
    const int tiles_y = OH / BROWS;
    const int oy0 = (blockIdx.y % tiles_y) * BROWS + threadIdx.y * YT;
    const int b = blockIdx.y / tiles_y;

    float acc[OCT][YT];
#pragma unroll
    for (int j = 0; j < OCT; j++) {
        float bj = bias[oc0 + j];
#pragma unroll
        for (int yy = 0; yy < YT; yy++) acc[j][yy] = bj;
    }

    constexpr int R = YT + 2;
    const float* inb = in + (size_t)b * IC * IH * IW;
    const int iy0 = oy0 - 1, ix0 = ox - 1;

    for (int ic = 0; ic < IC; ic++) {
        const float* ip = inb + (size_t)ic * IH * IW;
        float v[R][3];
#pragma unroll
        for (int r = 0; r < R; r++) {
            const int iy = iy0 + r;
            const bool yok = (unsigned)iy < (unsigned)IH;
            const float* rp = ip + iy * IW;
#pragma unroll
            for (int c = 0; c < 3; c++) {
                const int ix = ix0 + c;
                v[r][c] = (yok && (unsigned)ix < (unsigned)IW) ? rp[ix] : 0.f;
            }
        }
#pragma unroll
        for (int j = 0; j < OCT; j++) {
            const float* wj = wsh + (j * IC + ic) * 9;
            float w[9];
#pragma unroll
            for (int k = 0; k < 9; k++) w[k] = wj[k];
#pragma unroll
            for (int yy = 0; yy < YT; yy++) {
                float a = acc[j][yy];
#pragma unroll
                for (int ky = 0; ky < 3; ky++)
#pragma unroll
                    for (int kx = 0; kx < 3; kx++)
                        a = fmaf(v[yy + ky][kx], w[ky * 3 + kx], a);
                acc[j][yy] = a;
            }
        }
    }
    const float al = prelu_a[aidx];
    const int OHp = OH + 2;
#pragma unroll
    for (int yy = 0; yy < YT; yy++) {
        _Float16* ob =
            out + (((size_t)b * OHp + (oy0 + yy + 1)) * OWp + (ox + 1)) * OC;
#pragma unroll
        for (int j = 0; j < OCT; j++) {
            float y = acc[j][yy];
            y = y >= 0.f ? y : al * y;
            ob[oc0 + j] = (_Float16)y;
        }
    }
}

// ---------------------------------------------------------------------------
// MFMA f16 implicit-GEMM 3x3 conv (pad=1 via pre-zeroed halo), fused
// bias+PReLU. Activations padded NHWC f16. Block = 256 thr = 4 waves.
// Block tile: 128 output px (one row strip) x 32 oc. Wave: 32 px x 32 oc
// (2 M-frags x 2 N-frags), K = 9*IC over mfma_f32_16x16x32_f16 steps.
// A-frags read DIRECTLY from global NHWC (contiguous 16B/lane, fully
// coalesced for S=1). B (weights) staged once in LDS as [oc][k], row
// stride padded so KP%64==8 (2-way banks on ds_read_b128).
// ---------------------------------------------------------------------------
template <int S>
__global__ __launch_bounds__(256) void conv_mfma(
    const _Float16* __restrict__ in, const float* __restrict__ wgt,
    const float* __restrict__ bias, const float* __restrict__ prelu_a,
    int aidx, _Float16* __restrict__ out, int IC, int OC, int IWp, int OH,
    int OW, int OWp) {
    extern __shared__ _Float16 bsh[];
    const int K9 = 9 * IC;
    const int KP = K9 + ((72 - (K9 % 64)) % 64);
    const int oc0 = blockIdx.z * 32;
    // stage weights: bsh[ocL*KP + (pos*IC + ic)] = W[oc0+ocL][ic][pos]
    for (int i = threadIdx.x; i < 32 * K9; i += 256) {
        int ocL = i / K9, k = i - ocL * K9;
        int pos = k / IC, ic = k - pos * IC;
        bsh[ocL * KP + k] =
            (_Float16)wgt[((size_t)(oc0 + ocL) * IC + ic) * 9 + pos];
    }
    __syncthreads();

    const int lane = threadIdx.x & 63, w = threadIdx.x >> 6;
    const int l15 = lane & 15, g = lane >> 4;
    const int oy = blockIdx.y % OH, b = blockIdx.y / OH;
    const int xb = blockIdx.x * 128 + w * 32;
    const int IHp = OH * S + 2;
    const _Float16* inb = in + (size_t)b * IHp * IWp * IC;

    const float bv0 = bias[oc0 + l15], bv1 = bias[oc0 + 16 + l15];
    f32x4 acc00 = {bv0, bv0, bv0, bv0}, acc01 = {bv1, bv1, bv1, bv1};
    f32x4 acc10 = {bv0, bv0, bv0, bv0}, acc11 = {bv1, bv1, bv1, bv1};

    // lane-invariant-free offsets
    const size_t aoff0 = (size_t)(xb + l15) * S * IC + g * 8;
    const size_t aoff1 = aoff0 + (size_t)16 * S * IC;
    const int boff0 = l15 * KP + g * 8;
    const int boff1 = boff0 + 16 * KP;

    const int nicc = IC >> 5;
    for (int pos = 0; pos < 9; ++pos) {
        const int ky = pos / 3, kx = pos - ky * 3;
        const _Float16* ap = inb + ((size_t)(oy * S + ky) * IWp + kx) * IC;
        for (int icc = 0; icc < nicc; ++icc) {
            const int koff = pos * IC + icc * 32;
            half8 a0 = *(const half8*)(ap + aoff0 + icc * 32);
            half8 a1 = *(const half8*)(ap + aoff1 + icc * 32);
            half8 b0 = *(const half8*)(bsh + boff0 + koff);
            half8 b1 = *(const half8*)(bsh + boff1 + koff);
            acc00 = __builtin_amdgcn_mfma_f32_16x16x32_f16(a0, b0, acc00, 0, 0, 0);
            acc01 = __builtin_amdgcn_mfma_f32_16x16x32_f16(a0, b1, acc01, 0, 0, 0);
            acc10 = __builtin_amdgcn_mfma_f32_16x16x32_f16(a1, b0, acc10, 0, 0, 0);
            acc11 = __builtin_amdgcn_mfma_f32_16x16x32_f16(a1, b1, acc11, 0, 0, 0);
        }
    }

    const float al = prelu_a[aidx];
    _Float16* outb = out + (size_t)b * (OH + 2) * OWp * OC;
    // C/D layout: col(=oc) = lane&15, row(=px) = (lane>>4)*4 + reg  [m89]
#define STORE_FRAG(A, M, N)                                                   \
    {                                                                         \
        _Pragma("unroll") for (int r = 0; r < 4; ++r) {                       \
            int x = xb + (M)*16 + g * 4 + r;                                  \
            float v = (A)[r];                                                 \
            v = v >= 0.f ? v : al * v;                                        \
            outb[((size_t)(oy + 1) * OWp + (x + 1)) * OC + oc0 + (N)*16 +     \
                 l15] = (_Float16)v;                                          \
        }                                                                     \
    }
    STORE_FRAG(acc00, 0, 0)
    STORE_FRAG(acc01, 0, 1)
    STORE_FRAG(acc10, 1, 0)
    STORE_FRAG(acc11, 1, 1)
#undef STORE_FRAG
}

// ---------------------------------------------------------------------------
// z = param_scale * mean_c |(2*i0-1) - backwarp(2*i1-1, flow)| both dirs.
// ---------------------------------------------------------------------------
__global__ void compute_z2_kernel(const float* __restrict__ in0,
                                  const float* __restrict__ in1,
                                  const float* __restrict__ f01,
                                  const float* __restrict__ f10,
                                  const float* __restrict__ pscale,
                                  float* __restrict__ z0,
                                  float* __restrict__ z1) {
    int idx = blockIdx.x * blockDim.x + threadIdx.x;
    const int n = BB * HH * WWC;
    if (idx >= n) return;
    const int dir = blockIdx.y;
    const float* i0 = dir ? in1 : in0;
    const float* i1 = dir ? in0 : in1;
    const float* flow = dir ? f10 : f01;
    float* z = dir ? z1 : z0;
    int x = idx % WWC, y = (idx / WWC) % HH, b = idx / (WWC * HH);
    const float* fb = flow + (size_t)b * 2 * HH * WWC;
    float fx = fb[y * WWC + x];
    float fy = fb[HH * WWC + y * WWC + x];
    float px = fminf(fmaxf(x + fx, 0.f), WWC - 1.f);
    float py = fminf(fmaxf(y + fy, 0.f), HH - 1.f);
    float x0f = floorf(px), y0f = floorf(py);
    int x0 = (int)x0f, y0 = (int)y0f;
    int x1 = min(x0 + 1, WWC - 1), y1 = min(y0 + 1, HH - 1);
    float wx = px - x0f, wy = py - y0f;
    float w00 = (1.f - wx) * (1.f - wy), w10 = wx * (1.f - wy);
    float w01 = (1.f - wx) * wy, w11 = wx * wy;
    const float* ib0 = i0 + (size_t)b * 3 * HH * WWC;
    const float* ib1 = i1 + (size_t)b * 3 * HH * WWC;
    float err = 0.f;
#pragma unroll
    for (int c = 0; c < 3; c++) {
        const float* sp = ib1 + (size_t)c * HH * WWC;
        float wv = sp[y0 * WWC + x0] * w00 + sp[y0 * WWC + x1] * w10 +
                   sp[y1 * WWC + x0] * w01 + sp[y1 * WWC + x1] * w11;
        float p0 = 2.f * ib0[(size_t)c * HH * WWC + y * WWC + x] - 1.f;
        err += fabsf(p0 - (2.f * wv - 1.f));
    }
    z[idx] = pscale[0] * (err * (1.f / 3.f));
}

__device__ inline void atomic_add_f32(float* p, float v) {
    __hip_atomic_fetch_add(p, v, __ATOMIC_RELAXED, __HIP_MEMORY_SCOPE_AGENT);
}

__device__ inline float z_sample(const float* __restrict__ zb, int b, int sx,
                                 int sy, int s) {
    const float* zp = zb + (size_t)b * HH * WWC;
    if (s == 0) return zp[sy * WWC + sx];
    float sc = (float)(1 << s);
    float px = fminf(fmaxf((sx + 0.5f) * sc - 0.5f, 0.f), WWC - 1.f);
    float py = fminf(fmaxf((sy + 0.5f) * sc - 0.5f, 0.f), HH - 1.f);
    float x0f = floorf(px), y0f = floorf(py);
    int x0 = (int)x0f, y0 = (int)y0f;
    int x1 = min(x0 + 1, WWC - 1), y1 = min(y0 + 1, HH - 1);
    float wx = px - x0f, wy = py - y0f;
    return zp[y0 * WWC + x0] * (1.f - wx) * (1.f - wy) +
           zp[y0 * WWC + x1] * wx * (1.f - wy) +
           zp[y1 * WWC + x0] * (1.f - wx) * wy + zp[y1 * WWC + x1] * wx * wy;
}

// ---------------------------------------------------------------------------
// FAR pass: |fx|>15 or |fy|>15 sources via global-atomic scatter (rare).
// acc channel-interleaved (B, hh, ww, 3) = (vx, vy, ez).
// ---------------------------------------------------------------------------
__global__ void splat_far_kernel(const float* __restrict__ flow,
                                 const float* __restrict__ z,
                                 const float* __restrict__ tptr, int dir,
                                 float* __restrict__ acc, int s, int hh,
                                 int ww) {
    int idx = blockIdx.x * blockDim.x + threadIdx.x;
    const int n = BB * hh * ww;
    if (idx >= n) return;
    int x = idx % ww, y = (idx / ww) % hh, b = idx / (ww * hh);
    float tt = tptr[b];
    if (dir) tt = 1.f - tt;
    const float* fb = flow + (size_t)b * 2 * hh * ww;
    float fx = tt * fb[y * ww + x];
    float fy = tt * fb[hh * ww + y * ww + x];
    if (fmaxf(fabsf(fx), fabsf(fy)) <= 15.f) return;
    float zz = z_sample(z, b, x, y, s);
    float ez = expf(zz);
    float vx = -fx * ez, vy = -fy * ez;
    float tx = x + fx, ty = y + fy;
    float x0f = floorf(tx), y0f = floorf(ty);
    int x0 = (int)x0f, y0 = (int)y0f;
    int x1 = x0 + 1, y1 = y0 + 1;
    float wx1 = tx - x0f, wy1 = ty - y0f;
    float wx0 = 1.f - wx1, wy0 = 1.f - wy1;
    float* ab = acc + (size_t)b * 3 * hh * ww;
    int cxs[4] = {x0, x1, x0, x1};
    int cys[4] = {y0, y0, y1, y1};
    float cws[4] = {wx0 * wy0, wx1 * wy0, wx0 * wy1, wx1 * wy1};
#pragma unroll
    for (int k = 0; k < 4; k++) {
        int cx = cxs[k], cy = cys[k];
        float w = cws[k];
        if (cx >= 0 && cx < ww && cy >= 0 && cy < hh && w != 0.f) {
            float* p = ab + (size_t)3 * (cy * ww + cx);
            atomic_add_f32(p, vx * w);
            atomic_add_f32(p + 1, vy * w);
            atomic_add_f32(p + 2, ez * w);
        }
    }
}

// ---------------------------------------------------------------------------
// NEAR pass (gather): disjoint TH x TW tile per block, +/-16 halo sources,
// LDS accumulation, plain coalesced RMW flush. No global atomics.
// ---------------------------------------------------------------------------
template <int TH, int TW>
__global__ __launch_bounds__(256) void splat_gather_kernel(
    const float* __restrict__ flow, const float* __restrict__ z,
    const float* __restrict__ tptr, int dir, float* __restrict__ acc, int s,
    int hh, int ww) {
    constexpr int HALO = 16;
    constexpr int RH = TH + 2 * HALO, RW = TW + 2 * HALO;
    __shared__ float lacc[TH * TW * 3];
    const int x0 = blockIdx.x * TW, y0 = blockIdx.y * TH;
    const int b = blockIdx.z;
    const int tid = threadIdx.x;
    for (int i = tid; i < TH * TW * 3; i += 256) lacc[i] = 0.f;
    __syncthreads();
    float tt = tptr[b];
    if (dir) tt = 1.f - tt;
    const float* fb = flow + (size_t)b * 2 * hh * ww;
    for (int i = tid; i < RH * RW; i += 256) {
        int sy = y0 - HALO + i / RW;
        int sx = x0 - HALO + i % RW;
        if ((unsigned)sy >= (unsigned)hh || (unsigned)sx >= (unsigned)ww)
            continue;
        float fx = tt * fb[sy * ww + sx];
        float fy = tt * fb[(size_t)hh * ww + sy * ww + sx];
        if (fmaxf(fabsf(fx), fabsf(fy)) > 15.f) continue;
        float zz = z_sample(z, b, sx, sy, s);
        float ez = expf(zz);
        float vx = -fx * ez, vy = -fy * ez;
        float tx = sx + fx, ty = sy + fy;
        float xf = floorf(tx), yf = floorf(ty);
        int cx0 = (int)xf - x0, cy0 = (int)yf - y0;
        float wx1 = tx - xf, wy1 = ty - yf;
        float wx0 = 1.f - wx1, wy0 = 1.f - wy1;
#pragma unroll
        for (int k = 0; k < 4; k++) {
            int cx = cx0 + (k & 1), cy = cy0 + (k >> 1);
            float wgt = ((k & 1) ? wx1 : wx0) * ((k >> 1) ? wy1 : wy0);
            if ((unsigned)cx < (unsigned)TW && (unsigned)cy < (unsigned)TH &&
                wgt != 0.f) {
                float* p = lacc + (cy * TW + cx) * 3;
                atomicAdd(p, vx * wgt);
                atomicAdd(p + 1, vy * wgt);
                atomicAdd(p + 2, ez * wgt);
            }
        }
    }
    __syncthreads();
    float* ab = acc + (((size_t)b * hh + y0) * ww + x0) * 3;
    for (int i = tid; i < TH * TW * 3; i += 256) {
        int row = i / (TW * 3), rem = i % (TW * 3);
        float* gp = ab + (size_t)row * ww * 3 + rem;
        *gp = *gp + lacc[i];
    }
}

// ---------------------------------------------------------------------------
// Image backwarp (C=3, planar f32 src): flow = acc[0:2]/(acc[2]+eps).
// ---------------------------------------------------------------------------
__global__ void backwarp_out_kernel(const float* __restrict__ acc,
                                    const float* __restrict__ src,
                                    float* __restrict__ out, int C, int hh,
                                    int ww, int OCL, int coff) {
    int idx = blockIdx.x * blockDim.x + threadIdx.x;
    const int n = BB * hh * ww;
    if (idx >= n) return;
    int x = idx % ww, y = (idx / ww) % hh, b = idx / (ww * hh);
    const int plane = hh * ww;
    const float* ab = acc + (size_t)b * 3 * plane;
    int o = y * ww + x;
    const float* ap = ab + (size_t)3 * o;
    float den = ap[2] + EPSF;
    float fx = ap[0] / den;
    float fy = ap[1] / den;
    float px = fminf(fmaxf(x + fx, 0.f), ww - 1.f);
    float py = fminf(fmaxf(y + fy, 0.f), hh - 1.f);
    float x0f = floorf(px), y0f = floorf(py);
    int x0 = (int)x0f, y0 = (int)y0f;
    int x1 = min(x0 + 1, ww - 1), y1 = min(y0 + 1, hh - 1);
    float wx = px - x0f, wy = py - y0f;
    float w00 = (1.f - wx) * (1.f - wy), w10 = wx * (1.f - wy);
    float w01 = (1.f - wx) * wy, w11 = wx * wy;
    int i00 = y0 * ww + x0, i10 = y0 * ww + x1, i01 = y1 * ww + x0,
        i11 = y1 * ww + x1;
    const float* sb = src + (size_t)b * C * plane;
    float* ob = out + (((size_t)b * OCL + coff) * (size_t)plane) + o;
    for (int c = 0; c < C; c++) {
        const float* sp = sb + (size_t)c * plane;
        float v = sp[i00] * w00 + sp[i10] * w10 + sp[i01] * w01 + sp[i11] * w11;
        ob[(size_t)c * plane] = v;
    }
}

// ---------------------------------------------------------------------------
// Feature backwarp: src is PADDED NHWC f16; 4 contiguous C-wide gathers per
// pixel (half8-vectorized), f32 NCHW output slice.
// ---------------------------------------------------------------------------
__global__ void backwarp_feat_kernel(const float* __restrict__ acc,
                                     const _Float16* __restrict__ src,
                                     float* __restrict__ out, int C, int hh,
                                     int ww, int Wp, int OCL, int coff) {
    int idx = blockIdx.x * blockDim.x + threadIdx.x;
    const int n = BB * hh * ww;
    if (idx >= n) return;
    int x = idx % ww, y = (idx / ww) % hh, b = idx / (ww * hh);
    const int plane = hh * ww;
    const float* ap = acc + ((size_t)b * plane + y * ww + x) * 3;
    float den = ap[2] + EPSF;
    float fx = ap[0] / den;
    float fy = ap[1] / den;
    float px = fminf(fmaxf(x + fx, 0.f), ww - 1.f);
    float py = fminf(fmaxf(y + fy, 0.f), hh - 1.f);
    float x0f = floorf(px), y0f = floorf(py);
    int x0 = (int)x0f, y0 = (int)y0f;
    int x1 = min(x0 + 1, ww - 1), y1 = min(y0 + 1, hh - 1);
    float wx = px - x0f, wy = py - y0f;
    float w00 = (1.f - wx) * (1.f - wy), w10 = wx * (1.f - wy);
    float w01 = (1.f - wx) * wy, w11 = wx * wy;
    const int Hp = hh + 2;
    const _Float16* sb = src + (size_t)b * Hp * Wp * C;
    const _Float16* s00 = sb + ((size_t)(y0 + 1) * Wp + x0 + 1) * C;
    const _Float16* s10 = sb + ((size_t)(y0 + 1) * Wp + x1 + 1) * C;
    const _Float16* s01 = sb + ((size_t)(y1 + 1) * Wp + x0 + 1) * C;
    const _Float16* s11 = sb + ((size_t)(y1 + 1) * Wp + x1 + 1) * C;
    float* ob =
        out + (((size_t)b * OCL + coff) * (size_t)plane) + y * ww + x;
    for (int c8 = 0; c8 < C; c8 += 8) {
        half8 v00 = *(const half8*)(s00 + c8);
        half8 v10 = *(const half8*)(s10 + c8);
        half8 v01 = *(const half8*)(s01 + c8);
        half8 v11 = *(const half8*)(s11 + c8);
#pragma unroll
        for (int k = 0; k < 8; k++) {
            float v = (float)v00[k] * w00 + (float)v10[k] * w10 +
                      (float)v01[k] * w01 + (float)v11[k] * w11;
            ob[(size_t)(c8 + k) * plane] = v;
        }
    }
}

// ---------------------------------------------------------------------------
extern "C" void kernel_launch(void* const* d_in, const int* in_sizes, int n_in,
                              void* d_out, int out_size, void* d_ws,
                              size_t ws_size, hipStream_t stream) {
    const float* input0 = (const float*)d_in[0];
    const float* input1 = (const float*)d_in[1];
    const float* tgt = (const float*)d_in[2];
    const float* flows[2][3] = {
        {(const float*)d_in[3], (const float*)d_in[4], (const float*)d_in[5]},
        {(const float*)d_in[6], (const float*)d_in[7], (const float*)d_in[8]}};
    const float* w[6];
    const float* bs[6];
    for (int i = 0; i < 6; i++) {
        w[i] = (const float*)d_in[9 + 2 * i];
        bs[i] = (const float*)d_in[10 + 2 * i];
    }
    const float* prelu_a = (const float*)d_in[21];
    const float* pscale = (const float*)d_in[22];
    float* out = (float*)d_out;

    // ---- workspace layout ----
    // f16 padded NHWC buffers (halves):
    //  act1 (2,514,514,32) | fea1h[0] | fea1h[1]
    //  act2 (2,258,258,64) | fea2h[0] | fea2h[1]
    //  act3 (2,130,130,96) | fea3h[0] | fea3h[1]
    // then f32: zb[2] (2,512,512) each, acc (2,512,512,3)
    _Float16* hb = (_Float16*)d_ws;
    const size_t A1 = (size_t)2 * 514 * 514 * 32;  // 16,908,544
    const size_t A2 = (size_t)2 * 258 * 258 * 64;  //  8,520,192
    const size_t A3 = (size_t)2 * 130 * 130 * 96;  //  3,244,800
    _Float16* act1 = hb;
    _Float16* f1h[2] = {hb + A1, hb + 2 * A1};
    _Float16* act2 = hb + 3 * A1;
    _Float16* f2h[2] = {act2 + A2, act2 + 2 * A2};
    _Float16* act3 = act2 + 3 * A2;
    _Float16* f3h[2] = {act3 + A3, act3 + 2 * A3};
    const size_t h_total = 3 * (A1 + A2 + A3);
    float* fb32 = (float*)(hb + h_total);
    float* zb[2] = {fb32, fb32 + (size_t)BB * HH * WWC};
    float* acc = fb32 + (size_t)2 * BB * HH * WWC;

    // zero halos (and everything feeding convs); f3h halos never read.
    hipMemsetAsync(hb, 0, (3 * (A1 + A2) + A3) * sizeof(_Float16), stream);

    auto conv_m = [&](int S, const _Float16* in, int li, _Float16* o, int IC,
                      int OC, int IWp, int OH, int OW, int OWp) {
        const int K9 = 9 * IC;
        const int KP = K9 + ((72 - (K9 % 64)) % 64);
        size_t sm = (size_t)32 * KP * sizeof(_Float16);
        dim3 grd(OW / 128, OH * BB, OC / 32);
        if (S == 1)
            conv_mfma<1><<<grd, 256, sm, stream>>>(in, w[li], bs[li], prelu_a,
                                                   li, o, IC, OC, IWp, OH, OW,
                                                   OWp);
        else
            conv_mfma<2><<<grd, 256, sm, stream>>>(in, w[li], bs[li], prelu_a,
                                                   li, o, IC, OC, IWp, OH, OW,
                                                   OWp);
    };

    const float* inp[2] = {input0, input1};
    for (int i = 0; i < 2; i++) {
        {  // conv1: 3->32 @512, fp32 direct, f16 NHWC-padded out
            dim3 blk(64, 4);
            dim3 grd(512 / 64, (512 / 16) * BB, 32 / 16);
            size_t sm = (size_t)16 * 3 * 9 * sizeof(float);
            conv3x3_nhwc<16, 4><<<grd, blk, sm, stream>>>(
                inp[i], w[0], bs[0], prelu_a, 0, act1, 3, 32, 512, 512, 514);
        }
        conv_m(1, act1, 1, f1h[i], 32, 32, 514, 512, 512, 514);
        conv_m(2, f1h[i], 2, act2, 32, 64, 514, 256, 256, 258);
        conv_m(1, act2, 3, f2h[i], 64, 64, 258, 256, 256, 258);
        conv_m(2, f2h[i], 4, act3, 64, 96, 258, 128, 128, 130);
        conv_m(1, act3, 5, f3h[i], 96, 96, 130, 128, 128, 130);
    }

    {
        int n = BB * HH * WWC;
        dim3 grd((n + 255) / 256, 2);
        compute_z2_kernel<<<grd, 256, 0, stream>>>(
            input0, input1, flows[0][0], flows[1][0], pscale, zb[0], zb[1]);
    }

    const size_t l1off = (size_t)BB * 70 * 512 * 512;
    const size_t l2off = l1off + (size_t)BB * 128 * 256 * 256;

    for (int d = 0; d < 2; d++) {
        for (int s = 0; s < 3; s++) {
            int hh = HH >> s, ww = WWC >> s;
            int n = BB * hh * ww;
            hipMemsetAsync(acc, 0, (size_t)BB * 3 * hh * ww * sizeof(float),
                           stream);
            splat_far_kernel<<<(n + 255) / 256, 256, 0, stream>>>(
                flows[d][s], zb[d], tgt, d, acc, s, hh, ww);
            if (s < 2) {
                dim3 grd(ww / 64, hh / 32, BB);
                splat_gather_kernel<32, 64><<<grd, 256, 0, stream>>>(
                    flows[d][s], zb[d], tgt, d, acc, s, hh, ww);
            } else {
                dim3 grd(ww / 32, hh / 16, BB);
                splat_gather_kernel<16, 32><<<grd, 256, 0, stream>>>(
                    flows[d][s], zb[d], tgt, d, acc, s, hh, ww);
            }
            if (s == 0) {
                backwarp_out_kernel<<<(n + 255) / 256, 256, 0, stream>>>(
                    acc, inp[d], out, 3, 512, 512, 70, d ? 35 : 0);
                backwarp_feat_kernel<<<(n + 255) / 256, 256, 0, stream>>>(
                    acc, f1h[d], out, 32, 512, 512, 514, 70, d ? 38 : 3);
            } else if (s == 1) {
                backwarp_feat_kernel<<<(n + 255) / 256, 256, 0, stream>>>(
                    acc, f2h[d], out + l1off, 64, 256, 256, 258, 128,
                    d ? 64 : 0);
            } else {
                backwarp_feat_kernel<<<(n + 255) / 256, 256, 0, stream>>>(
                    acc, f3h[d], out + l2off, 96, 128, 128, 130, 192,
                    d ? 96 : 0);
            }
        }
    }
}

// Round 4
// 1283.842 us; speedup vs baseline: 1.8534x; 1.1249x over previous
//
#include <hip/hip_runtime.h>
#include <math.h>

#define EPSF 1e-7f
constexpr int BB = 2, HH = 512, WWC = 512;

typedef __attribute__((ext_vector_type(4))) float f32x4;
typedef __attribute__((ext_vector_type(8))) _Float16 half8;

// ---------------------------------------------------------------------------
// Halo-ring zero for padded NHWC f16 buffers (replaces 159MB blanket memset).
// blockIdx.y selects buffer; 4 batches each.
// ---------------------------------------------------------------------------
struct HZ {
    _Float16* p;
    int Hp, Wp, C;
};
struct HZ5 {
    HZ e[5];
};
__global__ void halo_zero_kernel(HZ5 z) {
    HZ d = z.e[blockIdx.y];
    const int wc = d.Wp * d.C;
    const int side = (d.Hp - 2) * d.C;
    const int perB = 2 * wc + 2 * side;
    const int total = 4 * perB;
    for (int i = blockIdx.x * 256 + threadIdx.x; i < total;
         i += gridDim.x * 256) {
        int b = i / perB, r = i % perB;
        int y, x, c;
        if (r < wc) {
            y = 0; x = r / d.C; c = r % d.C;
        } else if (r < 2 * wc) {
            int q = r - wc;
            y = d.Hp - 1; x = q / d.C; c = q % d.C;
        } else {
            int q = r - 2 * wc;
            int sd = q / side, q2 = q % side;
            y = 1 + q2 / d.C; x = sd ? d.Wp - 1 : 0; c = q2 % d.C;
        }
        d.p[(((size_t)b * d.Hp + y) * d.Wp + x) * d.C + c] = (_Float16)0.f;
    }
}

// ---------------------------------------------------------------------------
// conv1 (IC=3): direct fp32 conv, pad=1, fused bias+PReLU, PADDED NHWC f16
// out. Batch-4: b<2 -> image0, b>=2 -> image1 (inner batch = b&1).
// ---------------------------------------------------------------------------
template <int OCT, int YT>
__global__ __launch_bounds__(256) void conv3x3_nhwc(
    const float* __restrict__ in0, const float* __restrict__ in1,
    const float* __restrict__ wgt, const float* __restrict__ bias,
    const float* __restrict__ prelu_a, int aidx, _Float16* __restrict__ out,
    int IC, int OC, int IH, int IW, int OWp) {
    const int OH = IH, OW = IW;
    extern __shared__ float wsh[];
    const int oc0 = blockIdx.z * OCT;
    const int nw = OCT * IC * 9;
    const float* wsrc = wgt + (size_t)oc0 * IC * 9;
    for (int i = threadIdx.y * 64 + threadIdx.x; i < nw; i += 256)
        wsh[i] = wsrc[i];
    __syncthreads();

    const int ox = blockIdx.x * 64 + threadIdx.x;
    const int BROWS = 4 * YT;
    const int tiles_y = OH / BROWS;
    const int oy0 = (blockIdx.y % tiles_y) * BROWS + threadIdx.y * YT;
    const int b = blockIdx.y / tiles_y;  // 0..3

    float acc[OCT][YT];
#pragma unroll
    for (int j = 0; j < OCT; j++) {
        float bj = bias[oc0 + j];
#pragma unroll
        for (int yy = 0; yy < YT; yy++) acc[j][yy] = bj;
    }

    constexpr int R = YT + 2;
    const float* inb =
        (b < 2 ? in0 : in1) + (size_t)(b & 1) * IC * IH * IW;
    const int iy0 = oy0 - 1, ix0 = ox - 1;

    for (int ic = 0; ic < IC; ic++) {
        const float* ip = inb + (size_t)ic * IH * IW;
        float v[R][3];
#pragma unroll
        for (int r = 0; r < R; r++) {
            const int iy = iy0 + r;
            const bool yok = (unsigned)iy < (unsigned)IH;
            const float* rp = ip + iy * IW;
#pragma unroll
            for (int c = 0; c < 3; c++) {
                const int ix = ix0 + c;
                v[r][c] = (yok && (unsigned)ix < (unsigned)IW) ? rp[ix] : 0.f;
            }
        }
#pragma unroll
        for (int j = 0; j < OCT; j++) {
            const float* wj = wsh + (j * IC + ic) * 9;
            float w[9];
#pragma unroll
            for (int k = 0; k < 9; k++) w[k] = wj[k];
#pragma unroll
            for (int yy = 0; yy < YT; yy++) {
                float a = acc[j][yy];
#pragma unroll
                for (int ky = 0; ky < 3; ky++)
#pragma unroll
                    for (int kx = 0; kx < 3; kx++)
                        a = fmaf(v[yy + ky][kx], w[ky * 3 + kx], a);
                acc[j][yy] = a;
            }
        }
    }
    const float al = prelu_a[aidx];
    const int OHp = OH + 2;
#pragma unroll
    for (int yy = 0; yy < YT; yy++) {
        _Float16* ob =
            out + (((size_t)b * OHp + (oy0 + yy + 1)) * OWp + (ox + 1)) * OC;
#pragma unroll
        for (int j = 0; j < OCT; j++) {
            float y = acc[j][yy];
            y = y >= 0.f ? y : al * y;
            ob[oc0 + j] = (_Float16)y;
        }
    }
}

// ---------------------------------------------------------------------------
// MFMA f16 implicit-GEMM 3x3 conv (pad=1 via pre-zeroed halo), fused
// bias+PReLU. Padded NHWC f16 activations, batch-4. Block 256 thr = 4 waves;
// tile 128px x 32oc; wave 32px x 32oc; K=9*IC via mfma_f32_16x16x32_f16.
// A read directly from global NHWC (contiguous 16B/lane); B staged in LDS.
// ---------------------------------------------------------------------------
template <int S>
__global__ __launch_bounds__(256) void conv_mfma(
    const _Float16* __restrict__ in, const float* __restrict__ wgt,
    const float* __restrict__ bias, const float* __restrict__ prelu_a,
    int aidx, _Float16* __restrict__ out, int IC, int OC, int IWp, int OH,
    int OW, int OWp) {
    extern __shared__ _Float16 bsh[];
    const int K9 = 9 * IC;
    const int KP = K9 + ((72 - (K9 % 64)) % 64);
    const int oc0 = blockIdx.z * 32;
    for (int i = threadIdx.x; i < 32 * K9; i += 256) {
        int ocL = i / K9, k = i - ocL * K9;
        int pos = k / IC, ic = k - pos * IC;
        bsh[ocL * KP + k] =
            (_Float16)wgt[((size_t)(oc0 + ocL) * IC + ic) * 9 + pos];
    }
    __syncthreads();

    const int lane = threadIdx.x & 63, w = threadIdx.x >> 6;
    const int l15 = lane & 15, g = lane >> 4;
    const int oy = blockIdx.y % OH, b = blockIdx.y / OH;  // b in 0..3
    const int xb = blockIdx.x * 128 + w * 32;
    const int IHp = OH * S + 2;
    const _Float16* inb = in + (size_t)b * IHp * IWp * IC;

    const float bv0 = bias[oc0 + l15], bv1 = bias[oc0 + 16 + l15];
    f32x4 acc00 = {bv0, bv0, bv0, bv0}, acc01 = {bv1, bv1, bv1, bv1};
    f32x4 acc10 = {bv0, bv0, bv0, bv0}, acc11 = {bv1, bv1, bv1, bv1};

    const size_t aoff0 = (size_t)(xb + l15) * S * IC + g * 8;
    const size_t aoff1 = aoff0 + (size_t)16 * S * IC;
    const int boff0 = l15 * KP + g * 8;
    const int boff1 = boff0 + 16 * KP;

    const int nicc = IC >> 5;
    for (int pos = 0; pos < 9; ++pos) {
        const int ky = pos / 3, kx = pos - ky * 3;
        const _Float16* ap = inb + ((size_t)(oy * S + ky) * IWp + kx) * IC;
        for (int icc = 0; icc < nicc; ++icc) {
            const int koff = pos * IC + icc * 32;
            half8 a0 = *(const half8*)(ap + aoff0 + icc * 32);
            half8 a1 = *(const half8*)(ap + aoff1 + icc * 32);
            half8 b0 = *(const half8*)(bsh + boff0 + koff);
            half8 b1 = *(const half8*)(bsh + boff1 + koff);
            acc00 = __builtin_amdgcn_mfma_f32_16x16x32_f16(a0, b0, acc00, 0, 0, 0);
            acc01 = __builtin_amdgcn_mfma_f32_16x16x32_f16(a0, b1, acc01, 0, 0, 0);
            acc10 = __builtin_amdgcn_mfma_f32_16x16x32_f16(a1, b0, acc10, 0, 0, 0);
            acc11 = __builtin_amdgcn_mfma_f32_16x16x32_f16(a1, b1, acc11, 0, 0, 0);
        }
    }

    const float al = prelu_a[aidx];
    _Float16* outb = out + (size_t)b * (OH + 2) * OWp * OC;
#define STORE_FRAG(A, M, N)                                                   \
    {                                                                         \
        _Pragma("unroll") for (int r = 0; r < 4; ++r) {                       \
            int x = xb + (M)*16 + g * 4 + r;                                  \
            float v = (A)[r];                                                 \
            v = v >= 0.f ? v : al * v;                                        \
            outb[((size_t)(oy + 1) * OWp + (x + 1)) * OC + oc0 + (N)*16 +     \
                 l15] = (_Float16)v;                                          \
        }                                                                     \
    }
    STORE_FRAG(acc00, 0, 0)
    STORE_FRAG(acc01, 0, 1)
    STORE_FRAG(acc10, 1, 0)
    STORE_FRAG(acc11, 1, 1)
#undef STORE_FRAG
}

// ---------------------------------------------------------------------------
// z = param_scale * mean_c |(2*i0-1) - backwarp(2*i1-1, flow)|, both dirs.
// ---------------------------------------------------------------------------
__global__ void compute_z2_kernel(const float* __restrict__ in0,
                                  const float* __restrict__ in1,
                                  const float* __restrict__ f01,
                                  const float* __restrict__ f10,
                                  const float* __restrict__ pscale,
                                  float* __restrict__ z0,
                                  float* __restrict__ z1) {
    int idx = blockIdx.x * blockDim.x + threadIdx.x;
    const int n = BB * HH * WWC;
    if (idx >= n) return;
    const int dir = blockIdx.y;
    const float* i0 = dir ? in1 : in0;
    const float* i1 = dir ? in0 : in1;
    const float* flow = dir ? f10 : f01;
    float* z = dir ? z1 : z0;
    int x = idx % WWC, y = (idx / WWC) % HH, b = idx / (WWC * HH);
    const float* fb = flow + (size_t)b * 2 * HH * WWC;
    float fx = fb[y * WWC + x];
    float fy = fb[HH * WWC + y * WWC + x];
    float px = fminf(fmaxf(x + fx, 0.f), WWC - 1.f);
    float py = fminf(fmaxf(y + fy, 0.f), HH - 1.f);
    float x0f = floorf(px), y0f = floorf(py);
    int x0 = (int)x0f, y0 = (int)y0f;
    int x1 = min(x0 + 1, WWC - 1), y1 = min(y0 + 1, HH - 1);
    float wx = px - x0f, wy = py - y0f;
    float w00 = (1.f - wx) * (1.f - wy), w10 = wx * (1.f - wy);
    float w01 = (1.f - wx) * wy, w11 = wx * wy;
    const float* ib0 = i0 + (size_t)b * 3 * HH * WWC;
    const float* ib1 = i1 + (size_t)b * 3 * HH * WWC;
    float err = 0.f;
#pragma unroll
    for (int c = 0; c < 3; c++) {
        const float* sp = ib1 + (size_t)c * HH * WWC;
        float wv = sp[y0 * WWC + x0] * w00 + sp[y0 * WWC + x1] * w10 +
                   sp[y1 * WWC + x0] * w01 + sp[y1 * WWC + x1] * w11;
        float p0 = 2.f * ib0[(size_t)c * HH * WWC + y * WWC + x] - 1.f;
        err += fabsf(p0 - (2.f * wv - 1.f));
    }
    z[idx] = pscale[0] * (err * (1.f / 3.f));
}

__device__ inline void atomic_add_f32(float* p, float v) {
    __hip_atomic_fetch_add(p, v, __ATOMIC_RELAXED, __HIP_MEMORY_SCOPE_AGENT);
}

__device__ inline float z_sample(const float* __restrict__ zb, int b, int sx,
                                 int sy, int s) {
    const float* zp = zb + (size_t)b * HH * WWC;
    if (s == 0) return zp[sy * WWC + sx];
    float sc = (float)(1 << s);
    float px = fminf(fmaxf((sx + 0.5f) * sc - 0.5f, 0.f), WWC - 1.f);
    float py = fminf(fmaxf((sy + 0.5f) * sc - 0.5f, 0.f), HH - 1.f);
    float x0f = floorf(px), y0f = floorf(py);
    int x0 = (int)x0f, y0 = (int)y0f;
    int x1 = min(x0 + 1, WWC - 1), y1 = min(y0 + 1, HH - 1);
    float wx = px - x0f, wy = py - y0f;
    return zp[y0 * WWC + x0] * (1.f - wx) * (1.f - wy) +
           zp[y0 * WWC + x1] * wx * (1.f - wy) +
           zp[y1 * WWC + x0] * (1.f - wx) * wy + zp[y1 * WWC + x1] * wx * wy;
}

// ---------------------------------------------------------------------------
// FAR pass, both dirs (blockIdx.y): |f|>15 sources via global-atomic scatter.
// acc (dir, B, hh, ww, 3) channel-interleaved.
// ---------------------------------------------------------------------------
__global__ void splat_far_kernel(const float* __restrict__ fl0,
                                 const float* __restrict__ fl1,
                                 const float* __restrict__ z0,
                                 const float* __restrict__ z1,
                                 const float* __restrict__ tptr,
                                 float* __restrict__ acc, int s, int hh,
                                 int ww) {
    int idx = blockIdx.x * blockDim.x + threadIdx.x;
    const int n = BB * hh * ww;
    if (idx >= n) return;
    const int dir = blockIdx.y;
    const float* flow = dir ? fl1 : fl0;
    const float* z = dir ? z1 : z0;
    float* accd = acc + (size_t)dir * BB * 3 * hh * ww;
    int x = idx % ww, y = (idx / ww) % hh, b = idx / (ww * hh);
    float tt = tptr[b];
    if (dir) tt = 1.f - tt;
    const float* fb = flow + (size_t)b * 2 * hh * ww;
    float fx = tt * fb[y * ww + x];
    float fy = tt * fb[hh * ww + y * ww + x];
    if (fmaxf(fabsf(fx), fabsf(fy)) <= 15.f) return;
    float zz = z_sample(z, b, x, y, s);
    float ez = expf(zz);
    float vx = -fx * ez, vy = -fy * ez;
    float tx = x + fx, ty = y + fy;
    float x0f = floorf(tx), y0f = floorf(ty);
    int x0 = (int)x0f, y0 = (int)y0f;
    int x1 = x0 + 1, y1 = y0 + 1;
    float wx1 = tx - x0f, wy1 = ty - y0f;
    float wx0 = 1.f - wx1, wy0 = 1.f - wy1;
    float* ab = accd + (size_t)b * 3 * hh * ww;
    int cxs[4] = {x0, x1, x0, x1};
    int cys[4] = {y0, y0, y1, y1};
    float cws[4] = {wx0 * wy0, wx1 * wy0, wx0 * wy1, wx1 * wy1};
#pragma unroll
    for (int k = 0; k < 4; k++) {
        int cx = cxs[k], cy = cys[k];
        float w = cws[k];
        if (cx >= 0 && cx < ww && cy >= 0 && cy < hh && w != 0.f) {
            float* p = ab + (size_t)3 * (cy * ww + cx);
            atomic_add_f32(p, vx * w);
            atomic_add_f32(p + 1, vy * w);
            atomic_add_f32(p + 2, ez * w);
        }
    }
}

// ---------------------------------------------------------------------------
// NEAR pass (gather), both dirs via blockIdx.z = dir*BB + b. Disjoint
// TH x TW tile, +/-16 halo, LDS accumulation, plain coalesced RMW flush.
// ---------------------------------------------------------------------------
template <int TH, int TW>
__global__ __launch_bounds__(256) void splat_gather_kernel(
    const float* __restrict__ fl0, const float* __restrict__ fl1,
    const float* __restrict__ z0, const float* __restrict__ z1,
    const float* __restrict__ tptr, float* __restrict__ acc, int s, int hh,
    int ww) {
    constexpr int HALO = 16;
    constexpr int RH = TH + 2 * HALO, RW = TW + 2 * HALO;
    __shared__ float lacc[TH * TW * 3];
    const int x0 = blockIdx.x * TW, y0 = blockIdx.y * TH;
    const int comp = blockIdx.z;
    const int b = comp & (BB - 1), dir = comp / BB;
    const float* flow = dir ? fl1 : fl0;
    const float* z = dir ? z1 : z0;
    float* accd = acc + (size_t)dir * BB * 3 * hh * ww;
    const int tid = threadIdx.x;
    for (int i = tid; i < TH * TW * 3; i += 256) lacc[i] = 0.f;
    __syncthreads();
    float tt = tptr[b];
    if (dir) tt = 1.f - tt;
    const float* fb = flow + (size_t)b * 2 * hh * ww;
    for (int i = tid; i < RH * RW; i += 256) {
        int sy = y0 - HALO + i / RW;
        int sx = x0 - HALO + i % RW;
        if ((unsigned)sy >= (unsigned)hh || (unsigned)sx >= (unsigned)ww)
            continue;
        float fx = tt * fb[sy * ww + sx];
        float fy = tt * fb[(size_t)hh * ww + sy * ww + sx];
        if (fmaxf(fabsf(fx), fabsf(fy)) > 15.f) continue;
        float zz = z_sample(z, b, sx, sy, s);
        float ez = expf(zz);
        float vx = -fx * ez, vy = -fy * ez;
        float tx = sx + fx, ty = sy + fy;
        float xf = floorf(tx), yf = floorf(ty);
        int cx0 = (int)xf - x0, cy0 = (int)yf - y0;
        float wx1 = tx - xf, wy1 = ty - yf;
        float wx0 = 1.f - wx1, wy0 = 1.f - wy1;
#pragma unroll
        for (int k = 0; k < 4; k++) {
            int cx = cx0 + (k & 1), cy = cy0 + (k >> 1);
            float wgt = ((k & 1) ? wx1 : wx0) * ((k >> 1) ? wy1 : wy0);
            if ((unsigned)cx < (unsigned)TW && (unsigned)cy < (unsigned)TH &&
                wgt != 0.f) {
                float* p = lacc + (cy * TW + cx) * 3;
                atomicAdd(p, vx * wgt);
                atomicAdd(p + 1, vy * wgt);
                atomicAdd(p + 2, ez * wgt);
            }
        }
    }
    __syncthreads();
    float* ab = accd + (((size_t)b * hh + y0) * ww + x0) * 3;
    for (int i = tid; i < TH * TW * 3; i += 256) {
        int row = i / (TW * 3), rem = i % (TW * 3);
        float* gp = ab + (size_t)row * ww * 3 + rem;
        *gp = *gp + lacc[i];
    }
}

// ---------------------------------------------------------------------------
// s=0 fused backwarp, both dirs: out ch [dir*35 .. dir*35+2] = warped image
// (planar f32), [dir*35+3 .. dir*35+34] = warped fea1 (padded NHWC f16).
// ---------------------------------------------------------------------------
__global__ void backwarp_s0_kernel(const float* __restrict__ acc,
                                   const float* __restrict__ in0,
                                   const float* __restrict__ in1,
                                   const _Float16* __restrict__ f1,
                                   float* __restrict__ out) {
    int idx = blockIdx.x * blockDim.x + threadIdx.x;
    const int plane = HH * WWC;
    const int n = BB * plane;
    if (idx >= n) return;
    const int dir = blockIdx.y;
    int x = idx % WWC, y = (idx / WWC) % HH, b = idx / plane;
    const float* accd = acc + (size_t)dir * BB * 3 * plane;
    int o = y * WWC + x;
    const float* ap = accd + ((size_t)b * plane + o) * 3;
    float den = ap[2] + EPSF;
    float fx = ap[0] / den;
    float fy = ap[1] / den;
    float px = fminf(fmaxf(x + fx, 0.f), WWC - 1.f);
    float py = fminf(fmaxf(y + fy, 0.f), HH - 1.f);
    float x0f = floorf(px), y0f = floorf(py);
    int x0 = (int)x0f, y0 = (int)y0f;
    int x1 = min(x0 + 1, WWC - 1), y1 = min(y0 + 1, HH - 1);
    float wx = px - x0f, wy = py - y0f;
    float w00 = (1.f - wx) * (1.f - wy), w10 = wx * (1.f - wy);
    float w01 = (1.f - wx) * wy, w11 = wx * wy;
    float* ob = out + (((size_t)b * 70 + dir * 35) * (size_t)plane) + o;
    // image (planar f32)
    {
        const float* sb = (dir ? in1 : in0) + (size_t)b * 3 * plane;
        int i00 = y0 * WWC + x0, i10 = y0 * WWC + x1, i01 = y1 * WWC + x0,
            i11 = y1 * WWC + x1;
#pragma unroll
        for (int c = 0; c < 3; c++) {
            const float* sp = sb + (size_t)c * plane;
            float v = sp[i00] * w00 + sp[i10] * w10 + sp[i01] * w01 +
                      sp[i11] * w11;
            ob[(size_t)c * plane] = v;
        }
    }
    // fea1 (padded NHWC f16, batch = dir*2+b)
    {
        const int Wp = WWC + 2, C = 32;
        const _Float16* sb =
            f1 + (size_t)(dir * 2 + b) * (HH + 2) * Wp * C;
        const _Float16* s00 = sb + ((size_t)(y0 + 1) * Wp + x0 + 1) * C;
        const _Float16* s10 = sb + ((size_t)(y0 + 1) * Wp + x1 + 1) * C;
        const _Float16* s01 = sb + ((size_t)(y1 + 1) * Wp + x0 + 1) * C;
        const _Float16* s11 = sb + ((size_t)(y1 + 1) * Wp + x1 + 1) * C;
        float* obf = ob + (size_t)3 * plane;
        for (int c8 = 0; c8 < C; c8 += 8) {
            half8 v00 = *(const half8*)(s00 + c8);
            half8 v10 = *(const half8*)(s10 + c8);
            half8 v01 = *(const half8*)(s01 + c8);
            half8 v11 = *(const half8*)(s11 + c8);
#pragma unroll
            for (int k = 0; k < 8; k++) {
                float v = (float)v00[k] * w00 + (float)v10[k] * w10 +
                          (float)v01[k] * w01 + (float)v11[k] * w11;
                obf[(size_t)(c8 + k) * plane] = v;
            }
        }
    }
}

// ---------------------------------------------------------------------------
// s>0 feature backwarp, both dirs: src padded NHWC f16 batch dir*2+b,
// out slice coff = dir*C, OCL = 2*C.
// ---------------------------------------------------------------------------
__global__ void backwarp_feat_kernel(const float* __restrict__ acc,
                                     const _Float16* __restrict__ src,
                                     float* __restrict__ out, int C, int hh,
                                     int ww, int Wp) {
    int idx = blockIdx.x * blockDim.x + threadIdx.x;
    const int n = BB * hh * ww;
    if (idx >= n) return;
    const int dir = blockIdx.y;
    int x = idx % ww, y = (idx / ww) % hh, b = idx / (ww * hh);
    const int plane = hh * ww;
    const float* accd = acc + (size_t)dir * BB * 3 * plane;
    const float* ap = accd + ((size_t)b * plane + y * ww + x) * 3;
    float den = ap[2] + EPSF;
    float fx = ap[0] / den;
    float fy = ap[1] / den;
    float px = fminf(fmaxf(x + fx, 0.f), ww - 1.f);
    float py = fminf(fmaxf(y + fy, 0.f), hh - 1.f);
    float x0f = floorf(px), y0f = floorf(py);
    int x0 = (int)x0f, y0 = (int)y0f;
    int x1 = min(x0 + 1, ww - 1), y1 = min(y0 + 1, hh - 1);
    float wx = px - x0f, wy = py - y0f;
    float w00 = (1.f - wx) * (1.f - wy), w10 = wx * (1.f - wy);
    float w01 = (1.f - wx) * wy, w11 = wx * wy;
    const int Hp = hh + 2;
    const _Float16* sb = src + (size_t)(dir * 2 + b) * Hp * Wp * C;
    const _Float16* s00 = sb + ((size_t)(y0 + 1) * Wp + x0 + 1) * C;
    const _Float16* s10 = sb + ((size_t)(y0 + 1) * Wp + x1 + 1) * C;
    const _Float16* s01 = sb + ((size_t)(y1 + 1) * Wp + x0 + 1) * C;
    const _Float16* s11 = sb + ((size_t)(y1 + 1) * Wp + x1 + 1) * C;
    float* ob = out + (((size_t)b * 2 * C + dir * C) * (size_t)plane) +
                y * ww + x;
    for (int c8 = 0; c8 < C; c8 += 8) {
        half8 v00 = *(const half8*)(s00 + c8);
        half8 v10 = *(const half8*)(s10 + c8);
        half8 v01 = *(const half8*)(s01 + c8);
        half8 v11 = *(const half8*)(s11 + c8);
#pragma unroll
        for (int k = 0; k < 8; k++) {
            float v = (float)v00[k] * w00 + (float)v10[k] * w10 +
                      (float)v01[k] * w01 + (float)v11[k] * w11;
            ob[(size_t)(c8 + k) * plane] = v;
        }
    }
}

// ---------------------------------------------------------------------------
extern "C" void kernel_launch(void* const* d_in, const int* in_sizes, int n_in,
                              void* d_out, int out_size, void* d_ws,
                              size_t ws_size, hipStream_t stream) {
    const float* input0 = (const float*)d_in[0];
    const float* input1 = (const float*)d_in[1];
    const float* tgt = (const float*)d_in[2];
    const float* flows[2][3] = {
        {(const float*)d_in[3], (const float*)d_in[4], (const float*)d_in[5]},
        {(const float*)d_in[6], (const float*)d_in[7], (const float*)d_in[8]}};
    const float* w[6];
    const float* bs[6];
    for (int i = 0; i < 6; i++) {
        w[i] = (const float*)d_in[9 + 2 * i];
        bs[i] = (const float*)d_in[10 + 2 * i];
    }
    const float* prelu_a = (const float*)d_in[21];
    const float* pscale = (const float*)d_in[22];
    float* out = (float*)d_out;

    // ---- workspace layout (batch-4 = image*2 + batch) ----
    // f16 padded NHWC: act1(4,514,514,32) f1(same) act2(4,258,258,64)
    //                  f2(same) act3(4,130,130,96) f3(same)
    // f32: zb0, zb1 (B,512,512); acc (2dir,B,512,512,3)
    _Float16* hb = (_Float16*)d_ws;
    const size_t A1 = (size_t)4 * 514 * 514 * 32;  // 33,817,088
    const size_t A2 = (size_t)4 * 258 * 258 * 64;  // 17,040,384
    const size_t A3 = (size_t)4 * 130 * 130 * 96;  //  6,489,600
    _Float16* act1 = hb;
    _Float16* f1 = act1 + A1;
    _Float16* act2 = f1 + A1;
    _Float16* f2 = act2 + A2;
    _Float16* act3 = f2 + A2;
    _Float16* f3 = act3 + A3;
    float* fb32 = (float*)(f3 + A3);
    float* zb0 = fb32;
    float* zb1 = zb0 + (size_t)BB * HH * WWC;
    float* acc = zb1 + (size_t)BB * HH * WWC;  // 2*BB*3*512*512 floats max

    // halo rings only (f3 halo never read)
    {
        HZ5 hz;
        hz.e[0] = {act1, 514, 514, 32};
        hz.e[1] = {f1, 514, 514, 32};
        hz.e[2] = {act2, 258, 258, 64};
        hz.e[3] = {f2, 258, 258, 64};
        hz.e[4] = {act3, 130, 130, 96};
        dim3 grd(32, 5);
        halo_zero_kernel<<<grd, 256, 0, stream>>>(hz);
    }

    auto conv_m = [&](int S, const _Float16* in, int li, _Float16* o, int IC,
                      int OC, int IWp, int OH, int OW, int OWp) {
        const int K9 = 9 * IC;
        const int KP = K9 + ((72 - (K9 % 64)) % 64);
        size_t sm = (size_t)32 * KP * sizeof(_Float16);
        dim3 grd(OW / 128, OH * 4, OC / 32);
        if (S == 1)
            conv_mfma<1><<<grd, 256, sm, stream>>>(in, w[li], bs[li], prelu_a,
                                                   li, o, IC, OC, IWp, OH, OW,
                                                   OWp);
        else
            conv_mfma<2><<<grd, 256, sm, stream>>>(in, w[li], bs[li], prelu_a,
                                                   li, o, IC, OC, IWp, OH, OW,
                                                   OWp);
    };

    {  // conv1: 3->32 @512, fp32 direct, batch-4, f16 NHWC-padded out
        dim3 blk(64, 4);
        dim3 grd(512 / 64, (512 / 16) * 4, 32 / 16);
        size_t sm = (size_t)16 * 3 * 9 * sizeof(float);
        conv3x3_nhwc<16, 4><<<grd, blk, sm, stream>>>(
            input0, input1, w[0], bs[0], prelu_a, 0, act1, 3, 32, 512, 512,
            514);
    }
    conv_m(1, act1, 1, f1, 32, 32, 514, 512, 512, 514);
    conv_m(2, f1, 2, act2, 32, 64, 514, 256, 256, 258);
    conv_m(1, act2, 3, f2, 64, 64, 258, 256, 256, 258);
    conv_m(2, f2, 4, act3, 64, 96, 258, 128, 128, 130);
    conv_m(1, act3, 5, f3, 96, 96, 130, 128, 128, 130);

    {
        int n = BB * HH * WWC;
        dim3 grd((n + 255) / 256, 2);
        compute_z2_kernel<<<grd, 256, 0, stream>>>(
            input0, input1, flows[0][0], flows[1][0], pscale, zb0, zb1);
    }

    const size_t l1off = (size_t)BB * 70 * 512 * 512;
    const size_t l2off = l1off + (size_t)BB * 128 * 256 * 256;

    for (int s = 0; s < 3; s++) {
        int hh = HH >> s, ww = WWC >> s;
        int n = BB * hh * ww;
        hipMemsetAsync(acc, 0, (size_t)2 * BB * 3 * hh * ww * sizeof(float),
                       stream);
        {
            dim3 grd((n + 255) / 256, 2);
            splat_far_kernel<<<grd, 256, 0, stream>>>(
                flows[0][s], flows[1][s], zb0, zb1, tgt, acc, s, hh, ww);
        }
        if (s < 2) {
            dim3 grd(ww / 64, hh / 32, 2 * BB);
            splat_gather_kernel<32, 64><<<grd, 256, 0, stream>>>(
                flows[0][s], flows[1][s], zb0, zb1, tgt, acc, s, hh, ww);
        } else {
            dim3 grd(ww / 32, hh / 16, 2 * BB);
            splat_gather_kernel<16, 32><<<grd, 256, 0, stream>>>(
                flows[0][s], flows[1][s], zb0, zb1, tgt, acc, s, hh, ww);
        }
        dim3 grd((n + 255) / 256, 2);
        if (s == 0) {
            backwarp_s0_kernel<<<grd, 256, 0, stream>>>(acc, input0, input1,
                                                        f1, out);
        } else if (s == 1) {
            backwarp_feat_kernel<<<grd, 256, 0, stream>>>(
                acc, f2, out + l1off, 64, 256, 256, 258);
        } else {
            backwarp_feat_kernel<<<grd, 256, 0, stream>>>(
                acc, f3, out + l2off, 96, 128, 128, 130);
        }
    }
}

// Round 5
// 1000.219 us; speedup vs baseline: 2.3790x; 1.2836x over previous
//
#include <hip/hip_runtime.h>
#include <math.h>

#define EPSF 1e-7f
constexpr int BB = 2, HH = 512, WWC = 512;

typedef __attribute__((ext_vector_type(4))) float f32x4;
typedef __attribute__((ext_vector_type(8))) _Float16 half8;

// ---------------------------------------------------------------------------
// Halo-ring zero for padded NHWC f16 buffers. blockIdx.y selects buffer.
// ---------------------------------------------------------------------------
struct HZ {
    _Float16* p;
    int Hp, Wp, C;
};
struct HZ5 {
    HZ e[5];
};
__global__ void halo_zero_kernel(HZ5 z) {
    HZ d = z.e[blockIdx.y];
    const int wc = d.Wp * d.C;
    const int side = (d.Hp - 2) * d.C;
    const int perB = 2 * wc + 2 * side;
    const int total = 4 * perB;
    for (int i = blockIdx.x * 256 + threadIdx.x; i < total;
         i += gridDim.x * 256) {
        int b = i / perB, r = i % perB;
        int y, x, c;
        if (r < wc) {
            y = 0; x = r / d.C; c = r % d.C;
        } else if (r < 2 * wc) {
            int q = r - wc;
            y = d.Hp - 1; x = q / d.C; c = q % d.C;
        } else {
            int q = r - 2 * wc;
            int sd = q / side, q2 = q % side;
            y = 1 + q2 / d.C; x = sd ? d.Wp - 1 : 0; c = q2 % d.C;
        }
        d.p[(((size_t)b * d.Hp + y) * d.Wp + x) * d.C + c] = (_Float16)0.f;
    }
}

// ---------------------------------------------------------------------------
// One-time weight swizzle into per-lane MFMA fragment order:
// dst[(((ocblk*2+f)*NKC + kc)*64 + lane)*8 + j] = W[oc][ic][pos], f16,
// where oc = ocblk*32 + f*16 + (lane&15), k = kc*32 + (lane>>4)*8 + j,
// pos = k/IC, ic = k%IC.  Divisions OK here: runs once, ~200K elements.
// ---------------------------------------------------------------------------
struct WL {
    const float* w;
    _Float16* dst;
    int IC, OC;
};
struct WL5 {
    WL e[5];
};
__global__ void weight_swz_kernel(WL5 wl) {
    WL d = wl.e[blockIdx.y];
    const int IC = d.IC;
    const int K9 = 9 * IC;
    const int NKC = K9 / 32;
    const int total = d.OC * K9;
    for (int i = blockIdx.x * 256 + threadIdx.x; i < total;
         i += gridDim.x * 256) {
        int j = i & 7;
        int lane = (i >> 3) & 63;
        int rest = i >> 9;  // (ocblk*2+f)*NKC + kc
        int kc = rest % NKC;
        int fo = rest / NKC;
        int f = fo & 1, ocblk = fo >> 1;
        int l15 = lane & 15, g = lane >> 4;
        int k = kc * 32 + g * 8 + j;
        int pos = k / IC, ic = k % IC;
        int oc = ocblk * 32 + f * 16 + l15;
        d.dst[i] = (_Float16)d.w[((size_t)oc * IC + ic) * 9 + pos];
    }
}

// ---------------------------------------------------------------------------
// conv1 (IC=3): direct fp32 conv, pad=1, fused bias+PReLU, PADDED NHWC f16
// out. Batch-4: b<2 -> image0, b>=2 -> image1.
// ---------------------------------------------------------------------------
template <int OCT, int YT>
__global__ __launch_bounds__(256) void conv3x3_nhwc(
    const float* __restrict__ in0, const float* __restrict__ in1,
    const float* __restrict__ wgt, const float* __restrict__ bias,
    const float* __restrict__ prelu_a, int aidx, _Float16* __restrict__ out,
    int IC, int OC, int IH, int IW, int OWp) {
    const int OH = IH, OW = IW;
    extern __shared__ float wsh[];
    const int oc0 = blockIdx.z * OCT;
    const int nw = OCT * IC * 9;
    const float* wsrc = wgt + (size_t)oc0 * IC * 9;
    for (int i = threadIdx.y * 64 + threadIdx.x; i < nw; i += 256)
        wsh[i] = wsrc[i];
    __syncthreads();

    const int ox = blockIdx.x * 64 + threadIdx.x;
    const int BROWS = 4 * YT;
    const int tiles_y = OH / BROWS;
    const int oy0 = (blockIdx.y % tiles_y) * BROWS + threadIdx.y * YT;
    const int b = blockIdx.y / tiles_y;  // 0..3

    float acc[OCT][YT];
#pragma unroll
    for (int j = 0; j < OCT; j++) {
        float bj = bias[oc0 + j];
#pragma unroll
        for (int yy = 0; yy < YT; yy++) acc[j][yy] = bj;
    }

    constexpr int R = YT + 2;
    const float* inb = (b < 2 ? in0 : in1) + (size_t)(b & 1) * IC * IH * IW;
    const int iy0 = oy0 - 1, ix0 = ox - 1;

    for (int ic = 0; ic < IC; ic++) {
        const float* ip = inb + (size_t)ic * IH * IW;
        float v[R][3];
#pragma unroll
        for (int r = 0; r < R; r++) {
            const int iy = iy0 + r;
            const bool yok = (unsigned)iy < (unsigned)IH;
            const float* rp = ip + iy * IW;
#pragma unroll
            for (int c = 0; c < 3; c++) {
                const int ix = ix0 + c;
                v[r][c] = (yok && (unsigned)ix < (unsigned)IW) ? rp[ix] : 0.f;
            }
        }
#pragma unroll
        for (int j = 0; j < OCT; j++) {
            const float* wj = wsh + (j * IC + ic) * 9;
            float w[9];
#pragma unroll
            for (int k = 0; k < 9; k++) w[k] = wj[k];
#pragma unroll
            for (int yy = 0; yy < YT; yy++) {
                float a = acc[j][yy];
#pragma unroll
                for (int ky = 0; ky < 3; ky++)
#pragma unroll
                    for (int kx = 0; kx < 3; kx++)
                        a = fmaf(v[yy + ky][kx], w[ky * 3 + kx], a);
                acc[j][yy] = a;
            }
        }
    }
    const float al = prelu_a[aidx];
    const int OHp = OH + 2;
#pragma unroll
    for (int yy = 0; yy < YT; yy++) {
        _Float16* ob =
            out + (((size_t)b * OHp + (oy0 + yy + 1)) * OWp + (ox + 1)) * OC;
#pragma unroll
        for (int j = 0; j < OCT; j++) {
            float y = acc[j][yy];
            y = y >= 0.f ? y : al * y;
            ob[oc0 + j] = (_Float16)y;
        }
    }
}

// ---------------------------------------------------------------------------
// MFMA f16 implicit-GEMM 3x3 conv v2. Compile-time IC; pre-swizzled weights
// (contiguous per oc-block) staged via straight half8 memcpy; B-reads are
// streaming ds_read_b128 at lane*16 (conflict-free); ROWS output rows per
// block amortize staging. Fused bias+PReLU, padded NHWC f16, batch-4.
// ---------------------------------------------------------------------------
template <int S, int IC, int ROWS>
__global__ __launch_bounds__(256) void conv_mfma2(
    const _Float16* __restrict__ in, const _Float16* __restrict__ wswz,
    const float* __restrict__ bias, const float* __restrict__ prelu_a,
    int aidx, _Float16* __restrict__ out, int OC, int IWp, int OH, int OW,
    int OWp) {
    constexpr int NICC = IC / 32;
    constexpr int NKC = 9 * NICC;
    constexpr int NSTG = 2 * NKC * 512;  // halves per oc-block
    extern __shared__ _Float16 bsh[];
    const int oc0 = blockIdx.z * 32;
    {
        const _Float16* src = wswz + (size_t)blockIdx.z * NSTG;
        for (int i = threadIdx.x * 8; i < NSTG; i += 256 * 8)
            *(half8*)(bsh + i) = *(const half8*)(src + i);
    }
    __syncthreads();

    const int lane = threadIdx.x & 63, w = threadIdx.x >> 6;
    const int l15 = lane & 15, g = lane >> 4;
    const int ny = OH / ROWS;
    const int oy0 = (blockIdx.y % ny) * ROWS;
    const int b = blockIdx.y / ny;  // 0..3
    const int xb = blockIdx.x * 128 + w * 32;
    const int IHp = OH * S + 2;
    const _Float16* inb = in + (size_t)b * IHp * IWp * IC;
    const float bv0 = bias[oc0 + l15], bv1 = bias[oc0 + 16 + l15];
    const float al = prelu_a[aidx];
    const size_t aoff0 = (size_t)(xb + l15) * S * IC + g * 8;
    const size_t aoff1 = aoff0 + (size_t)16 * S * IC;
    _Float16* outb = out + (size_t)b * (OH + 2) * OWp * OC;

    for (int ry = 0; ry < ROWS; ++ry) {
        const int oy = oy0 + ry;
        f32x4 acc00 = {bv0, bv0, bv0, bv0}, acc01 = {bv1, bv1, bv1, bv1};
        f32x4 acc10 = {bv0, bv0, bv0, bv0}, acc11 = {bv1, bv1, bv1, bv1};
#pragma unroll
        for (int pos = 0; pos < 9; ++pos) {
            const int ky = pos / 3, kx = pos % 3;
            const _Float16* ap =
                inb + ((size_t)(oy * S + ky) * IWp + kx) * IC;
#pragma unroll
            for (int icc = 0; icc < NICC; ++icc) {
                const int kc = pos * NICC + icc;
                half8 a0 = *(const half8*)(ap + aoff0 + icc * 32);
                half8 a1 = *(const half8*)(ap + aoff1 + icc * 32);
                half8 b0 = *(const half8*)(bsh + kc * 512 + lane * 8);
                half8 b1 = *(const half8*)(bsh + (NKC + kc) * 512 + lane * 8);
                acc00 = __builtin_amdgcn_mfma_f32_16x16x32_f16(a0, b0, acc00,
                                                               0, 0, 0);
                acc01 = __builtin_amdgcn_mfma_f32_16x16x32_f16(a0, b1, acc01,
                                                               0, 0, 0);
                acc10 = __builtin_amdgcn_mfma_f32_16x16x32_f16(a1, b0, acc10,
                                                               0, 0, 0);
                acc11 = __builtin_amdgcn_mfma_f32_16x16x32_f16(a1, b1, acc11,
                                                               0, 0, 0);
            }
        }
#define STORE_FRAG(A, M, N)                                                   \
    {                                                                         \
        _Pragma("unroll") for (int r = 0; r < 4; ++r) {                       \
            int x = xb + (M)*16 + g * 4 + r;                                  \
            float v = (A)[r];                                                 \
            v = v >= 0.f ? v : al * v;                                        \
            outb[((size_t)(oy + 1) * OWp + (x + 1)) * OC + oc0 + (N)*16 +     \
                 l15] = (_Float16)v;                                          \
        }                                                                     \
    }
        STORE_FRAG(acc00, 0, 0)
        STORE_FRAG(acc01, 0, 1)
        STORE_FRAG(acc10, 1, 0)
        STORE_FRAG(acc11, 1, 1)
#undef STORE_FRAG
    }
}

// ---------------------------------------------------------------------------
// z = param_scale * mean_c |(2*i0-1) - backwarp(2*i1-1, flow)|, both dirs.
// ---------------------------------------------------------------------------
__global__ void compute_z2_kernel(const float* __restrict__ in0,
                                  const float* __restrict__ in1,
                                  const float* __restrict__ f01,
                                  const float* __restrict__ f10,
                                  const float* __restrict__ pscale,
                                  float* __restrict__ z0,
                                  float* __restrict__ z1) {
    int idx = blockIdx.x * blockDim.x + threadIdx.x;
    const int n = BB * HH * WWC;
    if (idx >= n) return;
    const int dir = blockIdx.y;
    const float* i0 = dir ? in1 : in0;
    const float* i1 = dir ? in0 : in1;
    const float* flow = dir ? f10 : f01;
    float* z = dir ? z1 : z0;
    int x = idx % WWC, y = (idx / WWC) % HH, b = idx / (WWC * HH);
    const float* fb = flow + (size_t)b * 2 * HH * WWC;
    float fx = fb[y * WWC + x];
    float fy = fb[HH * WWC + y * WWC + x];
    float px = fminf(fmaxf(x + fx, 0.f), WWC - 1.f);
    float py = fminf(fmaxf(y + fy, 0.f), HH - 1.f);
    float x0f = floorf(px), y0f = floorf(py);
    int x0 = (int)x0f, y0 = (int)y0f;
    int x1 = min(x0 + 1, WWC - 1), y1 = min(y0 + 1, HH - 1);
    float wx = px - x0f, wy = py - y0f;
    float w00 = (1.f - wx) * (1.f - wy), w10 = wx * (1.f - wy);
    float w01 = (1.f - wx) * wy, w11 = wx * wy;
    const float* ib0 = i0 + (size_t)b * 3 * HH * WWC;
    const float* ib1 = i1 + (size_t)b * 3 * HH * WWC;
    float err = 0.f;
#pragma unroll
    for (int c = 0; c < 3; c++) {
        const float* sp = ib1 + (size_t)c * HH * WWC;
        float wv = sp[y0 * WWC + x0] * w00 + sp[y0 * WWC + x1] * w10 +
                   sp[y1 * WWC + x0] * w01 + sp[y1 * WWC + x1] * w11;
        float p0 = 2.f * ib0[(size_t)c * HH * WWC + y * WWC + x] - 1.f;
        err += fabsf(p0 - (2.f * wv - 1.f));
    }
    z[idx] = pscale[0] * (err * (1.f / 3.f));
}

__device__ inline void atomic_add_f32(float* p, float v) {
    __hip_atomic_fetch_add(p, v, __ATOMIC_RELAXED, __HIP_MEMORY_SCOPE_AGENT);
}

__device__ inline float z_sample(const float* __restrict__ zb, int b, int sx,
                                 int sy, int s) {
    const float* zp = zb + (size_t)b * HH * WWC;
    if (s == 0) return zp[sy * WWC + sx];
    float sc = (float)(1 << s);
    float px = fminf(fmaxf((sx + 0.5f) * sc - 0.5f, 0.f), WWC - 1.f);
    float py = fminf(fmaxf((sy + 0.5f) * sc - 0.5f, 0.f), HH - 1.f);
    float x0f = floorf(px), y0f = floorf(py);
    int x0 = (int)x0f, y0 = (int)y0f;
    int x1 = min(x0 + 1, WWC - 1), y1 = min(y0 + 1, HH - 1);
    float wx = px - x0f, wy = py - y0f;
    return zp[y0 * WWC + x0] * (1.f - wx) * (1.f - wy) +
           zp[y0 * WWC + x1] * wx * (1.f - wy) +
           zp[y1 * WWC + x0] * (1.f - wx) * wy + zp[y1 * WWC + x1] * wx * wy;
}

// ---------------------------------------------------------------------------
// FAR pass, both dirs (blockIdx.y): |f|>15 sources via global-atomic scatter.
// ---------------------------------------------------------------------------
__global__ void splat_far_kernel(const float* __restrict__ fl0,
                                 const float* __restrict__ fl1,
                                 const float* __restrict__ z0,
                                 const float* __restrict__ z1,
                                 const float* __restrict__ tptr,
                                 float* __restrict__ acc, int s, int hh,
                                 int ww) {
    int idx = blockIdx.x * blockDim.x + threadIdx.x;
    const int n = BB * hh * ww;
    if (idx >= n) return;
    const int dir = blockIdx.y;
    const float* flow = dir ? fl1 : fl0;
    const float* z = dir ? z1 : z0;
    float* accd = acc + (size_t)dir * BB * 3 * hh * ww;
    int x = idx % ww, y = (idx / ww) % hh, b = idx / (ww * hh);
    float tt = tptr[b];
    if (dir) tt = 1.f - tt;
    const float* fb = flow + (size_t)b * 2 * hh * ww;
    float fx = tt * fb[y * ww + x];
    float fy = tt * fb[hh * ww + y * ww + x];
    if (fmaxf(fabsf(fx), fabsf(fy)) <= 15.f) return;
    float zz = z_sample(z, b, x, y, s);
    float ez = expf(zz);
    float vx = -fx * ez, vy = -fy * ez;
    float tx = x + fx, ty = y + fy;
    float x0f = floorf(tx), y0f = floorf(ty);
    int x0 = (int)x0f, y0 = (int)y0f;
    int x1 = x0 + 1, y1 = y0 + 1;
    float wx1 = tx - x0f, wy1 = ty - y0f;
    float wx0 = 1.f - wx1, wy0 = 1.f - wy1;
    float* ab = accd + (size_t)b * 3 * hh * ww;
    int cxs[4] = {x0, x1, x0, x1};
    int cys[4] = {y0, y0, y1, y1};
    float cws[4] = {wx0 * wy0, wx1 * wy0, wx0 * wy1, wx1 * wy1};
#pragma unroll
    for (int k = 0; k < 4; k++) {
        int cx = cxs[k], cy = cys[k];
        float w = cws[k];
        if (cx >= 0 && cx < ww && cy >= 0 && cy < hh && w != 0.f) {
            float* p = ab + (size_t)3 * (cy * ww + cx);
            atomic_add_f32(p, vx * w);
            atomic_add_f32(p + 1, vy * w);
            atomic_add_f32(p + 2, ez * w);
        }
    }
}

// ---------------------------------------------------------------------------
// NEAR pass (gather), both dirs via blockIdx.z = dir*BB + b.
// ---------------------------------------------------------------------------
template <int TH, int TW>
__global__ __launch_bounds__(256) void splat_gather_kernel(
    const float* __restrict__ fl0, const float* __restrict__ fl1,
    const float* __restrict__ z0, const float* __restrict__ z1,
    const float* __restrict__ tptr, float* __restrict__ acc, int s, int hh,
    int ww) {
    constexpr int HALO = 16;
    constexpr int RH = TH + 2 * HALO, RW = TW + 2 * HALO;
    __shared__ float lacc[TH * TW * 3];
    const int x0 = blockIdx.x * TW, y0 = blockIdx.y * TH;
    const int comp = blockIdx.z;
    const int b = comp & (BB - 1), dir = comp / BB;
    const float* flow = dir ? fl1 : fl0;
    const float* z = dir ? z1 : z0;
    float* accd = acc + (size_t)dir * BB * 3 * hh * ww;
    const int tid = threadIdx.x;
    for (int i = tid; i < TH * TW * 3; i += 256) lacc[i] = 0.f;
    __syncthreads();
    float tt = tptr[b];
    if (dir) tt = 1.f - tt;
    const float* fb = flow + (size_t)b * 2 * hh * ww;
    for (int i = tid; i < RH * RW; i += 256) {
        int sy = y0 - HALO + i / RW;
        int sx = x0 - HALO + i % RW;
        if ((unsigned)sy >= (unsigned)hh || (unsigned)sx >= (unsigned)ww)
            continue;
        float fx = tt * fb[sy * ww + sx];
        float fy = tt * fb[(size_t)hh * ww + sy * ww + sx];
        if (fmaxf(fabsf(fx), fabsf(fy)) > 15.f) continue;
        float zz = z_sample(z, b, sx, sy, s);
        float ez = expf(zz);
        float vx = -fx * ez, vy = -fy * ez;
        float tx = sx + fx, ty = sy + fy;
        float xf = floorf(tx), yf = floorf(ty);
        int cx0 = (int)xf - x0, cy0 = (int)yf - y0;
        float wx1 = tx - xf, wy1 = ty - yf;
        float wx0 = 1.f - wx1, wy0 = 1.f - wy1;
#pragma unroll
        for (int k = 0; k < 4; k++) {
            int cx = cx0 + (k & 1), cy = cy0 + (k >> 1);
            float wgt = ((k & 1) ? wx1 : wx0) * ((k >> 1) ? wy1 : wy0);
            if ((unsigned)cx < (unsigned)TW && (unsigned)cy < (unsigned)TH &&
                wgt != 0.f) {
                float* p = lacc + (cy * TW + cx) * 3;
                atomicAdd(p, vx * wgt);
                atomicAdd(p + 1, vy * wgt);
                atomicAdd(p + 2, ez * wgt);
            }
        }
    }
    __syncthreads();
    float* ab = accd + (((size_t)b * hh + y0) * ww + x0) * 3;
    for (int i = tid; i < TH * TW * 3; i += 256) {
        int row = i / (TW * 3), rem = i % (TW * 3);
        float* gp = ab + (size_t)row * ww * 3 + rem;
        *gp = *gp + lacc[i];
    }
}

// ---------------------------------------------------------------------------
// s=0 fused backwarp, both dirs: warped image (3ch planar f32) + warped fea1
// (32ch padded NHWC f16).
// ---------------------------------------------------------------------------
__global__ void backwarp_s0_kernel(const float* __restrict__ acc,
                                   const float* __restrict__ in0,
                                   const float* __restrict__ in1,
                                   const _Float16* __restrict__ f1,
                                   float* __restrict__ out) {
    int idx = blockIdx.x * blockDim.x + threadIdx.x;
    const int plane = HH * WWC;
    const int n = BB * plane;
    if (idx >= n) return;
    const int dir = blockIdx.y;
    int x = idx % WWC, y = (idx / WWC) % HH, b = idx / plane;
    const float* accd = acc + (size_t)dir * BB * 3 * plane;
    int o = y * WWC + x;
    const float* ap = accd + ((size_t)b * plane + o) * 3;
    float den = ap[2] + EPSF;
    float fx = ap[0] / den;
    float fy = ap[1] / den;
    float px = fminf(fmaxf(x + fx, 0.f), WWC - 1.f);
    float py = fminf(fmaxf(y + fy, 0.f), HH - 1.f);
    float x0f = floorf(px), y0f = floorf(py);
    int x0 = (int)x0f, y0 = (int)y0f;
    int x1 = min(x0 + 1, WWC - 1), y1 = min(y0 + 1, HH - 1);
    float wx = px - x0f, wy = py - y0f;
    float w00 = (1.f - wx) * (1.f - wy), w10 = wx * (1.f - wy);
    float w01 = (1.f - wx) * wy, w11 = wx * wy;
    float* ob = out + (((size_t)b * 70 + dir * 35) * (size_t)plane) + o;
    {
        const float* sb = (dir ? in1 : in0) + (size_t)b * 3 * plane;
        int i00 = y0 * WWC + x0, i10 = y0 * WWC + x1, i01 = y1 * WWC + x0,
            i11 = y1 * WWC + x1;
#pragma unroll
        for (int c = 0; c < 3; c++) {
            const float* sp = sb + (size_t)c * plane;
            float v = sp[i00] * w00 + sp[i10] * w10 + sp[i01] * w01 +
                      sp[i11] * w11;
            ob[(size_t)c * plane] = v;
        }
    }
    {
        const int Wp = WWC + 2, C = 32;
        const _Float16* sb = f1 + (size_t)(dir * 2 + b) * (HH + 2) * Wp * C;
        const _Float16* s00 = sb + ((size_t)(y0 + 1) * Wp + x0 + 1) * C;
        const _Float16* s10 = sb + ((size_t)(y0 + 1) * Wp + x1 + 1) * C;
        const _Float16* s01 = sb + ((size_t)(y1 + 1) * Wp + x0 + 1) * C;
        const _Float16* s11 = sb + ((size_t)(y1 + 1) * Wp + x1 + 1) * C;
        float* obf = ob + (size_t)3 * plane;
        for (int c8 = 0; c8 < C; c8 += 8) {
            half8 v00 = *(const half8*)(s00 + c8);
            half8 v10 = *(const half8*)(s10 + c8);
            half8 v01 = *(const half8*)(s01 + c8);
            half8 v11 = *(const half8*)(s11 + c8);
#pragma unroll
            for (int k = 0; k < 8; k++) {
                float v = (float)v00[k] * w00 + (float)v10[k] * w10 +
                          (float)v01[k] * w01 + (float)v11[k] * w11;
                obf[(size_t)(c8 + k) * plane] = v;
            }
        }
    }
}

// ---------------------------------------------------------------------------
// s>0 feature backwarp, both dirs.
// ---------------------------------------------------------------------------
__global__ void backwarp_feat_kernel(const float* __restrict__ acc,
                                     const _Float16* __restrict__ src,
                                     float* __restrict__ out, int C, int hh,
                                     int ww, int Wp) {
    int idx = blockIdx.x * blockDim.x + threadIdx.x;
    const int n = BB * hh * ww;
    if (idx >= n) return;
    const int dir = blockIdx.y;
    int x = idx % ww, y = (idx / ww) % hh, b = idx / (ww * hh);
    const int plane = hh * ww;
    const float* accd = acc + (size_t)dir * BB * 3 * plane;
    const float* ap = accd + ((size_t)b * plane + y * ww + x) * 3;
    float den = ap[2] + EPSF;
    float fx = ap[0] / den;
    float fy = ap[1] / den;
    float px = fminf(fmaxf(x + fx, 0.f), ww - 1.f);
    float py = fminf(fmaxf(y + fy, 0.f), hh - 1.f);
    float x0f = floorf(px), y0f = floorf(py);
    int x0 = (int)x0f, y0 = (int)y0f;
    int x1 = min(x0 + 1, ww - 1), y1 = min(y0 + 1, hh - 1);
    float wx = px - x0f, wy = py - y0f;
    float w00 = (1.f - wx) * (1.f - wy), w10 = wx * (1.f - wy);
    float w01 = (1.f - wx) * wy, w11 = wx * wy;
    const int Hp = hh + 2;
    const _Float16* sb = src + (size_t)(dir * 2 + b) * Hp * Wp * C;
    const _Float16* s00 = sb + ((size_t)(y0 + 1) * Wp + x0 + 1) * C;
    const _Float16* s10 = sb + ((size_t)(y0 + 1) * Wp + x1 + 1) * C;
    const _Float16* s01 = sb + ((size_t)(y1 + 1) * Wp + x0 + 1) * C;
    const _Float16* s11 = sb + ((size_t)(y1 + 1) * Wp + x1 + 1) * C;
    float* ob = out + (((size_t)b * 2 * C + dir * C) * (size_t)plane) +
                y * ww + x;
    for (int c8 = 0; c8 < C; c8 += 8) {
        half8 v00 = *(const half8*)(s00 + c8);
        half8 v10 = *(const half8*)(s10 + c8);
        half8 v01 = *(const half8*)(s01 + c8);
        half8 v11 = *(const half8*)(s11 + c8);
#pragma unroll
        for (int k = 0; k < 8; k++) {
            float v = (float)v00[k] * w00 + (float)v10[k] * w10 +
                      (float)v01[k] * w01 + (float)v11[k] * w11;
            ob[(size_t)(c8 + k) * plane] = v;
        }
    }
}

// ---------------------------------------------------------------------------
extern "C" void kernel_launch(void* const* d_in, const int* in_sizes, int n_in,
                              void* d_out, int out_size, void* d_ws,
                              size_t ws_size, hipStream_t stream) {
    const float* input0 = (const float*)d_in[0];
    const float* input1 = (const float*)d_in[1];
    const float* tgt = (const float*)d_in[2];
    const float* flows[2][3] = {
        {(const float*)d_in[3], (const float*)d_in[4], (const float*)d_in[5]},
        {(const float*)d_in[6], (const float*)d_in[7], (const float*)d_in[8]}};
    const float* w[6];
    const float* bs[6];
    for (int i = 0; i < 6; i++) {
        w[i] = (const float*)d_in[9 + 2 * i];
        bs[i] = (const float*)d_in[10 + 2 * i];
    }
    const float* prelu_a = (const float*)d_in[21];
    const float* pscale = (const float*)d_in[22];
    float* out = (float*)d_out;

    // ---- workspace layout (batch-4 = image*2 + batch) ----
    _Float16* hb = (_Float16*)d_ws;
    const size_t A1 = (size_t)4 * 514 * 514 * 32;  // 33,817,088
    const size_t A2 = (size_t)4 * 258 * 258 * 64;  // 17,040,384
    const size_t A3 = (size_t)4 * 130 * 130 * 96;  //  6,489,600
    _Float16* act1 = hb;
    _Float16* f1 = act1 + A1;
    _Float16* act2 = f1 + A1;
    _Float16* f2 = act2 + A2;
    _Float16* act3 = f2 + A2;
    _Float16* f3 = act3 + A3;
    float* fb32 = (float*)(f3 + A3);
    float* zb0 = fb32;
    float* zb1 = zb0 + (size_t)BB * HH * WWC;
    float* acc = zb1 + (size_t)BB * HH * WWC;
    // swizzled weights after acc (acc = 2*BB*3*512*512 floats max)
    _Float16* wswz = (_Float16*)(acc + (size_t)2 * BB * 3 * HH * WWC);
    const size_t WO2 = 0, WO3 = 9216, WO4 = 27648, WO5 = 64512, WO6 = 119808;

    // weight swizzle + halo rings (independent, cheap)
    {
        WL5 wlist;
        wlist.e[0] = {w[1], wswz + WO2, 32, 32};
        wlist.e[1] = {w[2], wswz + WO3, 32, 64};
        wlist.e[2] = {w[3], wswz + WO4, 64, 64};
        wlist.e[3] = {w[4], wswz + WO5, 64, 96};
        wlist.e[4] = {w[5], wswz + WO6, 96, 96};
        dim3 grd(16, 5);
        weight_swz_kernel<<<grd, 256, 0, stream>>>(wlist);
    }
    {
        HZ5 hz;
        hz.e[0] = {act1, 514, 514, 32};
        hz.e[1] = {f1, 514, 514, 32};
        hz.e[2] = {act2, 258, 258, 64};
        hz.e[3] = {f2, 258, 258, 64};
        hz.e[4] = {act3, 130, 130, 96};
        dim3 grd(32, 5);
        halo_zero_kernel<<<grd, 256, 0, stream>>>(hz);
    }

    {  // conv1: 3->32 @512, fp32 direct, batch-4
        dim3 blk(64, 4);
        dim3 grd(512 / 64, (512 / 16) * 4, 32 / 16);
        size_t sm = (size_t)16 * 3 * 9 * sizeof(float);
        conv3x3_nhwc<16, 4><<<grd, blk, sm, stream>>>(
            input0, input1, w[0], bs[0], prelu_a, 0, act1, 3, 32, 512, 512,
            514);
    }
    {  // conv2: 32->32 @512
        dim3 grd(512 / 128, (512 / 4) * 4, 1);
        conv_mfma2<1, 32, 4><<<grd, 256, 18432, stream>>>(
            act1, wswz + WO2, bs[1], prelu_a, 1, f1, 32, 514, 512, 512, 514);
    }
    {  // conv3: 32->64 @512->256, S=2
        dim3 grd(256 / 128, (256 / 4) * 4, 2);
        conv_mfma2<2, 32, 4><<<grd, 256, 18432, stream>>>(
            f1, wswz + WO3, bs[2], prelu_a, 2, act2, 64, 514, 256, 256, 258);
    }
    {  // conv4: 64->64 @256
        dim3 grd(256 / 128, (256 / 4) * 4, 2);
        conv_mfma2<1, 64, 4><<<grd, 256, 36864, stream>>>(
            act2, wswz + WO4, bs[3], prelu_a, 3, f2, 64, 258, 256, 256, 258);
    }
    {  // conv5: 64->96 @256->128, S=2
        dim3 grd(1, (128 / 2) * 4, 3);
        conv_mfma2<2, 64, 2><<<grd, 256, 36864, stream>>>(
            f2, wswz + WO5, bs[4], prelu_a, 4, act3, 96, 258, 128, 128, 130);
    }
    {  // conv6: 96->96 @128
        dim3 grd(1, (128 / 2) * 4, 3);
        conv_mfma2<1, 96, 2><<<grd, 256, 55296, stream>>>(
            act3, wswz + WO6, bs[5], prelu_a, 5, f3, 96, 130, 128, 128, 130);
    }

    {
        int n = BB * HH * WWC;
        dim3 grd((n + 255) / 256, 2);
        compute_z2_kernel<<<grd, 256, 0, stream>>>(
            input0, input1, flows[0][0], flows[1][0], pscale, zb0, zb1);
    }

    const size_t l1off = (size_t)BB * 70 * 512 * 512;
    const size_t l2off = l1off + (size_t)BB * 128 * 256 * 256;

    for (int s = 0; s < 3; s++) {
        int hh = HH >> s, ww = WWC >> s;
        int n = BB * hh * ww;
        hipMemsetAsync(acc, 0, (size_t)2 * BB * 3 * hh * ww * sizeof(float),
                       stream);
        {
            dim3 grd((n + 255) / 256, 2);
            splat_far_kernel<<<grd, 256, 0, stream>>>(
                flows[0][s], flows[1][s], zb0, zb1, tgt, acc, s, hh, ww);
        }
        if (s < 2) {
            dim3 grd(ww / 64, hh / 32, 2 * BB);
            splat_gather_kernel<32, 64><<<grd, 256, 0, stream>>>(
                flows[0][s], flows[1][s], zb0, zb1, tgt, acc, s, hh, ww);
        } else {
            dim3 grd(ww / 32, hh / 16, 2 * BB);
            splat_gather_kernel<16, 32><<<grd, 256, 0, stream>>>(
                flows[0][s], flows[1][s], zb0, zb1, tgt, acc, s, hh, ww);
        }
        dim3 grd((n + 255) / 256, 2);
        if (s == 0) {
            backwarp_s0_kernel<<<grd, 256, 0, stream>>>(acc, input0, input1,
                                                        f1, out);
        } else if (s == 1) {
            backwarp_feat_kernel<<<grd, 256, 0, stream>>>(
                acc, f2, out + l1off, 64, 256, 256, 258);
        } else {
            backwarp_feat_kernel<<<grd, 256, 0, stream>>>(
                acc, f3, out + l2off, 96, 128, 128, 130);
        }
    }
}

// Round 6
// 943.128 us; speedup vs baseline: 2.5230x; 1.0605x over previous
//
#include <hip/hip_runtime.h>
#include <math.h>

#define EPSF 1e-7f
constexpr int BB = 2, HH = 512, WWC = 512;

typedef __attribute__((ext_vector_type(4))) float f32x4;
typedef __attribute__((ext_vector_type(8))) _Float16 half8;

// ---------------------------------------------------------------------------
// Halo-ring zero for padded NHWC f16 buffers. blockIdx.y selects buffer.
// ---------------------------------------------------------------------------
struct HZ {
    _Float16* p;
    int Hp, Wp, C;
};
struct HZ5 {
    HZ e[5];
};
__global__ void halo_zero_kernel(HZ5 z) {
    HZ d = z.e[blockIdx.y];
    const int wc = d.Wp * d.C;
    const int side = (d.Hp - 2) * d.C;
    const int perB = 2 * wc + 2 * side;
    const int total = 4 * perB;
    for (int i = blockIdx.x * 256 + threadIdx.x; i < total;
         i += gridDim.x * 256) {
        int b = i / perB, r = i % perB;
        int y, x, c;
        if (r < wc) {
            y = 0; x = r / d.C; c = r % d.C;
        } else if (r < 2 * wc) {
            int q = r - wc;
            y = d.Hp - 1; x = q / d.C; c = q % d.C;
        } else {
            int q = r - 2 * wc;
            int sd = q / side, q2 = q % side;
            y = 1 + q2 / d.C; x = sd ? d.Wp - 1 : 0; c = q2 % d.C;
        }
        d.p[(((size_t)b * d.Hp + y) * d.Wp + x) * d.C + c] = (_Float16)0.f;
    }
}

// ---------------------------------------------------------------------------
// One-time weight swizzle into per-lane MFMA fragment order:
// dst[((N*NKC + kc)*64 + lane)*8 + j] = W[oc][ic][pos] as f16, where
// oc = N*16 + (lane&15), k = kc*32 + (lane>>4)*8 + j, pos = k/IC, ic = k%IC.
// Layout is LINEAR in N-frag index -> kernels read B directly from global.
// ---------------------------------------------------------------------------
struct WL {
    const float* w;
    _Float16* dst;
    int IC, OC;
};
struct WL5 {
    WL e[5];
};
__global__ void weight_swz_kernel(WL5 wl) {
    WL d = wl.e[blockIdx.y];
    const int IC = d.IC;
    const int K9 = 9 * IC;
    const int NKC = K9 / 32;
    const int total = d.OC * K9;
    for (int i = blockIdx.x * 256 + threadIdx.x; i < total;
         i += gridDim.x * 256) {
        int j = i & 7;
        int lane = (i >> 3) & 63;
        int rest = i >> 9;  // N*NKC + kc
        int kc = rest % NKC;
        int N = rest / NKC;
        int l15 = lane & 15, g = lane >> 4;
        int k = kc * 32 + g * 8 + j;
        int pos = k / IC, ic = k % IC;
        int oc = N * 16 + l15;
        d.dst[i] = (_Float16)d.w[((size_t)oc * IC + ic) * 9 + pos];
    }
}

// ---------------------------------------------------------------------------
// conv1 (IC=3): direct fp32 conv, pad=1, fused bias+PReLU, PADDED NHWC f16
// out. Batch-4: b<2 -> image0, b>=2 -> image1.
// ---------------------------------------------------------------------------
template <int OCT, int YT>
__global__ __launch_bounds__(256) void conv3x3_nhwc(
    const float* __restrict__ in0, const float* __restrict__ in1,
    const float* __restrict__ wgt, const float* __restrict__ bias,
    const float* __restrict__ prelu_a, int aidx, _Float16* __restrict__ out,
    int IC, int OC, int IH, int IW, int OWp) {
    const int OH = IH, OW = IW;
    extern __shared__ float wsh[];
    const int oc0 = blockIdx.z * OCT;
    const int nw = OCT * IC * 9;
    const float* wsrc = wgt + (size_t)oc0 * IC * 9;
    for (int i = threadIdx.y * 64 + threadIdx.x; i < nw; i += 256)
        wsh[i] = wsrc[i];
    __syncthreads();

    const int ox = blockIdx.x * 64 + threadIdx.x;
    const int BROWS = 4 * YT;
    const int tiles_y = OH / BROWS;
    const int oy0 = (blockIdx.y % tiles_y) * BROWS + threadIdx.y * YT;
    const int b = blockIdx.y / tiles_y;  // 0..3

    float acc[OCT][YT];
#pragma unroll
    for (int j = 0; j < OCT; j++) {
        float bj = bias[oc0 + j];
#pragma unroll
        for (int yy = 0; yy < YT; yy++) acc[j][yy] = bj;
    }

    constexpr int R = YT + 2;
    const float* inb = (b < 2 ? in0 : in1) + (size_t)(b & 1) * IC * IH * IW;
    const int iy0 = oy0 - 1, ix0 = ox - 1;

    for (int ic = 0; ic < IC; ic++) {
        const float* ip = inb + (size_t)ic * IH * IW;
        float v[R][3];
#pragma unroll
        for (int r = 0; r < R; r++) {
            const int iy = iy0 + r;
            const bool yok = (unsigned)iy < (unsigned)IH;
            const float* rp = ip + iy * IW;
#pragma unroll
            for (int c = 0; c < 3; c++) {
                const int ix = ix0 + c;
                v[r][c] = (yok && (unsigned)ix < (unsigned)IW) ? rp[ix] : 0.f;
            }
        }
#pragma unroll
        for (int j = 0; j < OCT; j++) {
            const float* wj = wsh + (j * IC + ic) * 9;
            float w[9];
#pragma unroll
            for (int k = 0; k < 9; k++) w[k] = wj[k];
#pragma unroll
            for (int yy = 0; yy < YT; yy++) {
                float a = acc[j][yy];
#pragma unroll
                for (int ky = 0; ky < 3; ky++)
#pragma unroll
                    for (int kx = 0; kx < 3; kx++)
                        a = fmaf(v[yy + ky][kx], w[ky * 3 + kx], a);
                acc[j][yy] = a;
            }
        }
    }
    const float al = prelu_a[aidx];
    const int OHp = OH + 2;
#pragma unroll
    for (int yy = 0; yy < YT; yy++) {
        _Float16* ob =
            out + (((size_t)b * OHp + (oy0 + yy + 1)) * OWp + (ox + 1)) * OC;
#pragma unroll
        for (int j = 0; j < OCT; j++) {
            float y = acc[j][yy];
            y = y >= 0.f ? y : al * y;
            ob[oc0 + j] = (_Float16)y;
        }
    }
}

// ---------------------------------------------------------------------------
// MFMA f16 implicit-GEMM 3x3 conv v3. No LDS at all: B fragments read
// directly from pre-swizzled global weights (identical bytes across waves ->
// L1 broadcast-cached). Wave tile = 64 px (MFR=4 M-frags) x full OC
// (NFR=OC/16 N-frags) -> A traffic per MFMA = 512/NFR bytes. Block = 4
// waves covering WPR*64 px x (4/WPR) rows. Fused bias+PReLU, padded NHWC
// f16 activations, batch-4.
// ---------------------------------------------------------------------------
template <int S, int IC, int OC, int WPR>
__global__ __launch_bounds__(256) void conv_mfma3(
    const _Float16* __restrict__ in, const _Float16* __restrict__ wswz,
    const float* __restrict__ bias, const float* __restrict__ prelu_a,
    int aidx, _Float16* __restrict__ out, int IWp, int OH, int OW, int OWp) {
    constexpr int NICC = IC / 32;
    constexpr int NKC = 9 * NICC;
    constexpr int NFR = OC / 16;
    constexpr int RPB = 4 / WPR;
    const int lane = threadIdx.x & 63, w = threadIdx.x >> 6;
    const int l15 = lane & 15, g = lane >> 4;
    const int ny = OH / RPB;
    const int oy = (blockIdx.y % ny) * RPB + w / WPR;
    const int b = blockIdx.y / ny;  // 0..3
    const int xb = blockIdx.x * (WPR * 64) + (w % WPR) * 64;
    const int IHp = OH * S + 2;
    const _Float16* inb = in + (size_t)b * IHp * IWp * IC;
    const float al = prelu_a[aidx];

    f32x4 acc[4][NFR];
#pragma unroll
    for (int n = 0; n < NFR; ++n) {
        float bv = bias[n * 16 + l15];
#pragma unroll
        for (int m = 0; m < 4; ++m) acc[m][n] = {bv, bv, bv, bv};
    }
    size_t aoff[4];
#pragma unroll
    for (int m = 0; m < 4; ++m)
        aoff[m] = (size_t)(xb + m * 16 + l15) * S * IC + g * 8;
    const int boff = lane * 8;

#pragma unroll
    for (int pos = 0; pos < 9; ++pos) {
        const int ky = pos / 3, kx = pos % 3;
        const _Float16* ap = inb + ((size_t)(oy * S + ky) * IWp + kx) * IC;
#pragma unroll
        for (int icc = 0; icc < NICC; ++icc) {
            const int kc = pos * NICC + icc;
            half8 a[4];
#pragma unroll
            for (int m = 0; m < 4; ++m)
                a[m] = *(const half8*)(ap + aoff[m] + icc * 32);
#pragma unroll
            for (int n = 0; n < NFR; ++n) {
                half8 bf = *(const half8*)(wswz +
                                           (size_t)(n * NKC + kc) * 512 +
                                           boff);
#pragma unroll
                for (int m = 0; m < 4; ++m)
                    acc[m][n] = __builtin_amdgcn_mfma_f32_16x16x32_f16(
                        a[m], bf, acc[m][n], 0, 0, 0);
            }
        }
    }
    _Float16* outb = out + (size_t)b * (OH + 2) * OWp * OC;
#pragma unroll
    for (int m = 0; m < 4; ++m)
#pragma unroll
        for (int n = 0; n < NFR; ++n)
#pragma unroll
            for (int r = 0; r < 4; ++r) {
                int x = xb + m * 16 + g * 4 + r;
                float v = acc[m][n][r];
                v = v >= 0.f ? v : al * v;
                outb[((size_t)(oy + 1) * OWp + (x + 1)) * OC + n * 16 + l15] =
                    (_Float16)v;
            }
}

// ---------------------------------------------------------------------------
// z = param_scale * mean_c |(2*i0-1) - backwarp(2*i1-1, flow)|, both dirs.
// ---------------------------------------------------------------------------
__global__ void compute_z2_kernel(const float* __restrict__ in0,
                                  const float* __restrict__ in1,
                                  const float* __restrict__ f01,
                                  const float* __restrict__ f10,
                                  const float* __restrict__ pscale,
                                  float* __restrict__ z0,
                                  float* __restrict__ z1) {
    int idx = blockIdx.x * blockDim.x + threadIdx.x;
    const int n = BB * HH * WWC;
    if (idx >= n) return;
    const int dir = blockIdx.y;
    const float* i0 = dir ? in1 : in0;
    const float* i1 = dir ? in0 : in1;
    const float* flow = dir ? f10 : f01;
    float* z = dir ? z1 : z0;
    int x = idx % WWC, y = (idx / WWC) % HH, b = idx / (WWC * HH);
    const float* fb = flow + (size_t)b * 2 * HH * WWC;
    float fx = fb[y * WWC + x];
    float fy = fb[HH * WWC + y * WWC + x];
    float px = fminf(fmaxf(x + fx, 0.f), WWC - 1.f);
    float py = fminf(fmaxf(y + fy, 0.f), HH - 1.f);
    float x0f = floorf(px), y0f = floorf(py);
    int x0 = (int)x0f, y0 = (int)y0f;
    int x1 = min(x0 + 1, WWC - 1), y1 = min(y0 + 1, HH - 1);
    float wx = px - x0f, wy = py - y0f;
    float w00 = (1.f - wx) * (1.f - wy), w10 = wx * (1.f - wy);
    float w01 = (1.f - wx) * wy, w11 = wx * wy;
    const float* ib0 = i0 + (size_t)b * 3 * HH * WWC;
    const float* ib1 = i1 + (size_t)b * 3 * HH * WWC;
    float err = 0.f;
#pragma unroll
    for (int c = 0; c < 3; c++) {
        const float* sp = ib1 + (size_t)c * HH * WWC;
        float wv = sp[y0 * WWC + x0] * w00 + sp[y0 * WWC + x1] * w10 +
                   sp[y1 * WWC + x0] * w01 + sp[y1 * WWC + x1] * w11;
        float p0 = 2.f * ib0[(size_t)c * HH * WWC + y * WWC + x] - 1.f;
        err += fabsf(p0 - (2.f * wv - 1.f));
    }
    z[idx] = pscale[0] * (err * (1.f / 3.f));
}

__device__ inline void atomic_add_f32(float* p, float v) {
    __hip_atomic_fetch_add(p, v, __ATOMIC_RELAXED, __HIP_MEMORY_SCOPE_AGENT);
}

__device__ inline float z_sample(const float* __restrict__ zb, int b, int sx,
                                 int sy, int s) {
    const float* zp = zb + (size_t)b * HH * WWC;
    if (s == 0) return zp[sy * WWC + sx];
    float sc = (float)(1 << s);
    float px = fminf(fmaxf((sx + 0.5f) * sc - 0.5f, 0.f), WWC - 1.f);
    float py = fminf(fmaxf((sy + 0.5f) * sc - 0.5f, 0.f), HH - 1.f);
    float x0f = floorf(px), y0f = floorf(py);
    int x0 = (int)x0f, y0 = (int)y0f;
    int x1 = min(x0 + 1, WWC - 1), y1 = min(y0 + 1, HH - 1);
    float wx = px - x0f, wy = py - y0f;
    return zp[y0 * WWC + x0] * (1.f - wx) * (1.f - wy) +
           zp[y0 * WWC + x1] * wx * (1.f - wy) +
           zp[y1 * WWC + x0] * (1.f - wx) * wy + zp[y1 * WWC + x1] * wx * wy;
}

// ---------------------------------------------------------------------------
// FAR pass, both dirs (blockIdx.y): |f|>15 sources via global-atomic scatter.
// ---------------------------------------------------------------------------
__global__ void splat_far_kernel(const float* __restrict__ fl0,
                                 const float* __restrict__ fl1,
                                 const float* __restrict__ z0,
                                 const float* __restrict__ z1,
                                 const float* __restrict__ tptr,
                                 float* __restrict__ acc, int s, int hh,
                                 int ww) {
    int idx = blockIdx.x * blockDim.x + threadIdx.x;
    const int n = BB * hh * ww;
    if (idx >= n) return;
    const int dir = blockIdx.y;
    const float* flow = dir ? fl1 : fl0;
    const float* z = dir ? z1 : z0;
    float* accd = acc + (size_t)dir * BB * 3 * hh * ww;
    int x = idx % ww, y = (idx / ww) % hh, b = idx / (ww * hh);
    float tt = tptr[b];
    if (dir) tt = 1.f - tt;
    const float* fb = flow + (size_t)b * 2 * hh * ww;
    float fx = tt * fb[y * ww + x];
    float fy = tt * fb[hh * ww + y * ww + x];
    if (fmaxf(fabsf(fx), fabsf(fy)) <= 15.f) return;
    float zz = z_sample(z, b, x, y, s);
    float ez = expf(zz);
    float vx = -fx * ez, vy = -fy * ez;
    float tx = x + fx, ty = y + fy;
    float x0f = floorf(tx), y0f = floorf(ty);
    int x0 = (int)x0f, y0 = (int)y0f;
    int x1 = x0 + 1, y1 = y0 + 1;
    float wx1 = tx - x0f, wy1 = ty - y0f;
    float wx0 = 1.f - wx1, wy0 = 1.f - wy1;
    float* ab = accd + (size_t)b * 3 * hh * ww;
    int cxs[4] = {x0, x1, x0, x1};
    int cys[4] = {y0, y0, y1, y1};
    float cws[4] = {wx0 * wy0, wx1 * wy0, wx0 * wy1, wx1 * wy1};
#pragma unroll
    for (int k = 0; k < 4; k++) {
        int cx = cxs[k], cy = cys[k];
        float w = cws[k];
        if (cx >= 0 && cx < ww && cy >= 0 && cy < hh && w != 0.f) {
            float* p = ab + (size_t)3 * (cy * ww + cx);
            atomic_add_f32(p, vx * w);
            atomic_add_f32(p + 1, vy * w);
            atomic_add_f32(p + 2, ez * w);
        }
    }
}

// ---------------------------------------------------------------------------
// NEAR pass (gather), both dirs via blockIdx.z = dir*BB + b.
// ---------------------------------------------------------------------------
template <int TH, int TW>
__global__ __launch_bounds__(256) void splat_gather_kernel(
    const float* __restrict__ fl0, const float* __restrict__ fl1,
    const float* __restrict__ z0, const float* __restrict__ z1,
    const float* __restrict__ tptr, float* __restrict__ acc, int s, int hh,
    int ww) {
    constexpr int HALO = 16;
    constexpr int RH = TH + 2 * HALO, RW = TW + 2 * HALO;
    __shared__ float lacc[TH * TW * 3];
    const int x0 = blockIdx.x * TW, y0 = blockIdx.y * TH;
    const int comp = blockIdx.z;
    const int b = comp & (BB - 1), dir = comp / BB;
    const float* flow = dir ? fl1 : fl0;
    const float* z = dir ? z1 : z0;
    float* accd = acc + (size_t)dir * BB * 3 * hh * ww;
    const int tid = threadIdx.x;
    for (int i = tid; i < TH * TW * 3; i += 256) lacc[i] = 0.f;
    __syncthreads();
    float tt = tptr[b];
    if (dir) tt = 1.f - tt;
    const float* fb = flow + (size_t)b * 2 * hh * ww;
    for (int i = tid; i < RH * RW; i += 256) {
        int sy = y0 - HALO + i / RW;
        int sx = x0 - HALO + i % RW;
        if ((unsigned)sy >= (unsigned)hh || (unsigned)sx >= (unsigned)ww)
            continue;
        float fx = tt * fb[sy * ww + sx];
        float fy = tt * fb[(size_t)hh * ww + sy * ww + sx];
        if (fmaxf(fabsf(fx), fabsf(fy)) > 15.f) continue;
        float zz = z_sample(z, b, sx, sy, s);
        float ez = expf(zz);
        float vx = -fx * ez, vy = -fy * ez;
        float tx = sx + fx, ty = sy + fy;
        float xf = floorf(tx), yf = floorf(ty);
        int cx0 = (int)xf - x0, cy0 = (int)yf - y0;
        float wx1 = tx - xf, wy1 = ty - yf;
        float wx0 = 1.f - wx1, wy0 = 1.f - wy1;
#pragma unroll
        for (int k = 0; k < 4; k++) {
            int cx = cx0 + (k & 1), cy = cy0 + (k >> 1);
            float wgt = ((k & 1) ? wx1 : wx0) * ((k >> 1) ? wy1 : wy0);
            if ((unsigned)cx < (unsigned)TW && (unsigned)cy < (unsigned)TH &&
                wgt != 0.f) {
                float* p = lacc + (cy * TW + cx) * 3;
                atomicAdd(p, vx * wgt);
                atomicAdd(p + 1, vy * wgt);
                atomicAdd(p + 2, ez * wgt);
            }
        }
    }
    __syncthreads();
    float* ab = accd + (((size_t)b * hh + y0) * ww + x0) * 3;
    for (int i = tid; i < TH * TW * 3; i += 256) {
        int row = i / (TW * 3), rem = i % (TW * 3);
        float* gp = ab + (size_t)row * ww * 3 + rem;
        *gp = *gp + lacc[i];
    }
}

// ---------------------------------------------------------------------------
// s=0 fused backwarp, both dirs: warped image (3ch planar f32) + warped fea1
// (32ch padded NHWC f16).
// ---------------------------------------------------------------------------
__global__ void backwarp_s0_kernel(const float* __restrict__ acc,
                                   const float* __restrict__ in0,
                                   const float* __restrict__ in1,
                                   const _Float16* __restrict__ f1,
                                   float* __restrict__ out) {
    int idx = blockIdx.x * blockDim.x + threadIdx.x;
    const int plane = HH * WWC;
    const int n = BB * plane;
    if (idx >= n) return;
    const int dir = blockIdx.y;
    int x = idx % WWC, y = (idx / WWC) % HH, b = idx / plane;
    const float* accd = acc + (size_t)dir * BB * 3 * plane;
    int o = y * WWC + x;
    const float* ap = accd + ((size_t)b * plane + o) * 3;
    float den = ap[2] + EPSF;
    float fx = ap[0] / den;
    float fy = ap[1] / den;
    float px = fminf(fmaxf(x + fx, 0.f), WWC - 1.f);
    float py = fminf(fmaxf(y + fy, 0.f), HH - 1.f);
    float x0f = floorf(px), y0f = floorf(py);
    int x0 = (int)x0f, y0 = (int)y0f;
    int x1 = min(x0 + 1, WWC - 1), y1 = min(y0 + 1, HH - 1);
    float wx = px - x0f, wy = py - y0f;
    float w00 = (1.f - wx) * (1.f - wy), w10 = wx * (1.f - wy);
    float w01 = (1.f - wx) * wy, w11 = wx * wy;
    float* ob = out + (((size_t)b * 70 + dir * 35) * (size_t)plane) + o;
    {
        const float* sb = (dir ? in1 : in0) + (size_t)b * 3 * plane;
        int i00 = y0 * WWC + x0, i10 = y0 * WWC + x1, i01 = y1 * WWC + x0,
            i11 = y1 * WWC + x1;
#pragma unroll
        for (int c = 0; c < 3; c++) {
            const float* sp = sb + (size_t)c * plane;
            float v = sp[i00] * w00 + sp[i10] * w10 + sp[i01] * w01 +
                      sp[i11] * w11;
            ob[(size_t)c * plane] = v;
        }
    }
    {
        const int Wp = WWC + 2, C = 32;
        const _Float16* sb = f1 + (size_t)(dir * 2 + b) * (HH + 2) * Wp * C;
        const _Float16* s00 = sb + ((size_t)(y0 + 1) * Wp + x0 + 1) * C;
        const _Float16* s10 = sb + ((size_t)(y0 + 1) * Wp + x1 + 1) * C;
        const _Float16* s01 = sb + ((size_t)(y1 + 1) * Wp + x0 + 1) * C;
        const _Float16* s11 = sb + ((size_t)(y1 + 1) * Wp + x1 + 1) * C;
        float* obf = ob + (size_t)3 * plane;
        for (int c8 = 0; c8 < C; c8 += 8) {
            half8 v00 = *(const half8*)(s00 + c8);
            half8 v10 = *(const half8*)(s10 + c8);
            half8 v01 = *(const half8*)(s01 + c8);
            half8 v11 = *(const half8*)(s11 + c8);
#pragma unroll
            for (int k = 0; k < 8; k++) {
                float v = (float)v00[k] * w00 + (float)v10[k] * w10 +
                          (float)v01[k] * w01 + (float)v11[k] * w11;
                obf[(size_t)(c8 + k) * plane] = v;
            }
        }
    }
}

// ---------------------------------------------------------------------------
// s>0 feature backwarp, both dirs.
// ---------------------------------------------------------------------------
__global__ void backwarp_feat_kernel(const float* __restrict__ acc,
                                     const _Float16* __restrict__ src,
                                     float* __restrict__ out, int C, int hh,
                                     int ww, int Wp) {
    int idx = blockIdx.x * blockDim.x + threadIdx.x;
    const int n = BB * hh * ww;
    if (idx >= n) return;
    const int dir = blockIdx.y;
    int x = idx % ww, y = (idx / ww) % hh, b = idx / (ww * hh);
    const int plane = hh * ww;
    const float* accd = acc + (size_t)dir * BB * 3 * plane;
    const float* ap = accd + ((size_t)b * plane + y * ww + x) * 3;
    float den = ap[2] + EPSF;
    float fx = ap[0] / den;
    float fy = ap[1] / den;
    float px = fminf(fmaxf(x + fx, 0.f), ww - 1.f);
    float py = fminf(fmaxf(y + fy, 0.f), hh - 1.f);
    float x0f = floorf(px), y0f = floorf(py);
    int x0 = (int)x0f, y0 = (int)y0f;
    int x1 = min(x0 + 1, ww - 1), y1 = min(y0 + 1, hh - 1);
    float wx = px - x0f, wy = py - y0f;
    float w00 = (1.f - wx) * (1.f - wy), w10 = wx * (1.f - wy);
    float w01 = (1.f - wx) * wy, w11 = wx * wy;
    const int Hp = hh + 2;
    const _Float16* sb = src + (size_t)(dir * 2 + b) * Hp * Wp * C;
    const _Float16* s00 = sb + ((size_t)(y0 + 1) * Wp + x0 + 1) * C;
    const _Float16* s10 = sb + ((size_t)(y0 + 1) * Wp + x1 + 1) * C;
    const _Float16* s01 = sb + ((size_t)(y1 + 1) * Wp + x0 + 1) * C;
    const _Float16* s11 = sb + ((size_t)(y1 + 1) * Wp + x1 + 1) * C;
    float* ob = out + (((size_t)b * 2 * C + dir * C) * (size_t)plane) +
                y * ww + x;
    for (int c8 = 0; c8 < C; c8 += 8) {
        half8 v00 = *(const half8*)(s00 + c8);
        half8 v10 = *(const half8*)(s10 + c8);
        half8 v01 = *(const half8*)(s01 + c8);
        half8 v11 = *(const half8*)(s11 + c8);
#pragma unroll
        for (int k = 0; k < 8; k++) {
            float v = (float)v00[k] * w00 + (float)v10[k] * w10 +
                      (float)v01[k] * w01 + (float)v11[k] * w11;
            ob[(size_t)(c8 + k) * plane] = v;
        }
    }
}

// ---------------------------------------------------------------------------
extern "C" void kernel_launch(void* const* d_in, const int* in_sizes, int n_in,
                              void* d_out, int out_size, void* d_ws,
                              size_t ws_size, hipStream_t stream) {
    const float* input0 = (const float*)d_in[0];
    const float* input1 = (const float*)d_in[1];
    const float* tgt = (const float*)d_in[2];
    const float* flows[2][3] = {
        {(const float*)d_in[3], (const float*)d_in[4], (const float*)d_in[5]},
        {(const float*)d_in[6], (const float*)d_in[7], (const float*)d_in[8]}};
    const float* w[6];
    const float* bs[6];
    for (int i = 0; i < 6; i++) {
        w[i] = (const float*)d_in[9 + 2 * i];
        bs[i] = (const float*)d_in[10 + 2 * i];
    }
    const float* prelu_a = (const float*)d_in[21];
    const float* pscale = (const float*)d_in[22];
    float* out = (float*)d_out;

    // ---- workspace layout (batch-4 = image*2 + batch) ----
    _Float16* hb = (_Float16*)d_ws;
    const size_t A1 = (size_t)4 * 514 * 514 * 32;  // 33,817,088
    const size_t A2 = (size_t)4 * 258 * 258 * 64;  // 17,040,384
    const size_t A3 = (size_t)4 * 130 * 130 * 96;  //  6,489,600
    _Float16* act1 = hb;
    _Float16* f1 = act1 + A1;
    _Float16* act2 = f1 + A1;
    _Float16* f2 = act2 + A2;
    _Float16* act3 = f2 + A2;
    _Float16* f3 = act3 + A3;
    float* fb32 = (float*)(f3 + A3);
    float* zb0 = fb32;
    float* zb1 = zb0 + (size_t)BB * HH * WWC;
    float* acc = zb1 + (size_t)BB * HH * WWC;
    // swizzled weights after acc (acc = 2*BB*3*512*512 floats max)
    _Float16* wswz = (_Float16*)(acc + (size_t)2 * BB * 3 * HH * WWC);
    const size_t WO2 = 0, WO3 = 9216, WO4 = 27648, WO5 = 64512, WO6 = 119808;

    // weight swizzle + halo rings (independent, cheap)
    {
        WL5 wlist;
        wlist.e[0] = {w[1], wswz + WO2, 32, 32};
        wlist.e[1] = {w[2], wswz + WO3, 32, 64};
        wlist.e[2] = {w[3], wswz + WO4, 64, 64};
        wlist.e[3] = {w[4], wswz + WO5, 64, 96};
        wlist.e[4] = {w[5], wswz + WO6, 96, 96};
        dim3 grd(16, 5);
        weight_swz_kernel<<<grd, 256, 0, stream>>>(wlist);
    }
    {
        HZ5 hz;
        hz.e[0] = {act1, 514, 514, 32};
        hz.e[1] = {f1, 514, 514, 32};
        hz.e[2] = {act2, 258, 258, 64};
        hz.e[3] = {f2, 258, 258, 64};
        hz.e[4] = {act3, 130, 130, 96};
        dim3 grd(32, 5);
        halo_zero_kernel<<<grd, 256, 0, stream>>>(hz);
    }

    {  // conv1: 3->32 @512, fp32 direct, batch-4
        dim3 blk(64, 4);
        dim3 grd(512 / 64, (512 / 16) * 4, 32 / 16);
        size_t sm = (size_t)16 * 3 * 9 * sizeof(float);
        conv3x3_nhwc<16, 4><<<grd, blk, sm, stream>>>(
            input0, input1, w[0], bs[0], prelu_a, 0, act1, 3, 32, 512, 512,
            514);
    }
    {  // conv2: 32->32 @512
        dim3 grd(512 / 256, 512 * 4, 1);
        conv_mfma3<1, 32, 32, 4><<<grd, 256, 0, stream>>>(
            act1, wswz + WO2, bs[1], prelu_a, 1, f1, 514, 512, 512, 514);
    }
    {  // conv3: 32->64 @512->256, S=2
        dim3 grd(1, 256 * 4, 1);
        conv_mfma3<2, 32, 64, 4><<<grd, 256, 0, stream>>>(
            f1, wswz + WO3, bs[2], prelu_a, 2, act2, 514, 256, 256, 258);
    }
    {  // conv4: 64->64 @256
        dim3 grd(1, 256 * 4, 1);
        conv_mfma3<1, 64, 64, 4><<<grd, 256, 0, stream>>>(
            act2, wswz + WO4, bs[3], prelu_a, 3, f2, 258, 256, 256, 258);
    }
    {  // conv5: 64->96 @256->128, S=2
        dim3 grd(1, (128 / 2) * 4, 1);
        conv_mfma3<2, 64, 96, 2><<<grd, 256, 0, stream>>>(
            f2, wswz + WO5, bs[4], prelu_a, 4, act3, 258, 128, 128, 130);
    }
    {  // conv6: 96->96 @128
        dim3 grd(1, (128 / 2) * 4, 1);
        conv_mfma3<1, 96, 96, 2><<<grd, 256, 0, stream>>>(
            act3, wswz + WO6, bs[5], prelu_a, 5, f3, 130, 128, 128, 130);
    }

    {
        int n = BB * HH * WWC;
        dim3 grd((n + 255) / 256, 2);
        compute_z2_kernel<<<grd, 256, 0, stream>>>(
            input0, input1, flows[0][0], flows[1][0], pscale, zb0, zb1);
    }

    const size_t l1off = (size_t)BB * 70 * 512 * 512;
    const size_t l2off = l1off + (size_t)BB * 128 * 256 * 256;

    for (int s = 0; s < 3; s++) {
        int hh = HH >> s, ww = WWC >> s;
        int n = BB * hh * ww;
        hipMemsetAsync(acc, 0, (size_t)2 * BB * 3 * hh * ww * sizeof(float),
                       stream);
        {
            dim3 grd((n + 255) / 256, 2);
            splat_far_kernel<<<grd, 256, 0, stream>>>(
                flows[0][s], flows[1][s], zb0, zb1, tgt, acc, s, hh, ww);
        }
        if (s < 2) {
            dim3 grd(ww / 64, hh / 32, 2 * BB);
            splat_gather_kernel<32, 64><<<grd, 256, 0, stream>>>(
                flows[0][s], flows[1][s], zb0, zb1, tgt, acc, s, hh, ww);
        } else {
            dim3 grd(ww / 32, hh / 16, 2 * BB);
            splat_gather_kernel<16, 32><<<grd, 256, 0, stream>>>(
                flows[0][s], flows[1][s], zb0, zb1, tgt, acc, s, hh, ww);
        }
        dim3 grd((n + 255) / 256, 2);
        if (s == 0) {
            backwarp_s0_kernel<<<grd, 256, 0, stream>>>(acc, input0, input1,
                                                        f1, out);
        } else if (s == 1) {
            backwarp_feat_kernel<<<grd, 256, 0, stream>>>(
                acc, f2, out + l1off, 64, 256, 256, 258);
        } else {
            backwarp_feat_kernel<<<grd, 256, 0, stream>>>(
                acc, f3, out + l2off, 96, 128, 128, 130);
        }
    }
}